// Round 1
// baseline (5535.940 us; speedup 1.0000x reference)
//
#include <hip/hip_runtime.h>
#include <hip/hip_bf16.h>

#define N_NODES_IN_DIM 128
#define HID_DIM 256
#define OUT_DIM 40

// ---------------- degree count ----------------
__global__ __launch_bounds__(256) void count_edges(const int* __restrict__ dst,
                                                   float* __restrict__ cnt, int E) {
    int e = blockIdx.x * 256 + threadIdx.x;
    if (e < E) atomicAdd(&cnt[dst[e]], 1.0f);
}

__global__ __launch_bounds__(256) void recip_cnt(const float* __restrict__ cnt,
                                                 float* __restrict__ inv, int N) {
    int i = blockIdx.x * 256 + threadIdx.x;
    if (i < N) inv[i] = 1.0f / fmaxf(cnt[i], 1.0f);
}

// ---------------- scatter-add: agg[dst] += feat[src] ----------------
// D = 4 << LOGP floats per row; one thread handles 4 consecutive floats.
template <int LOGP>
__global__ __launch_bounds__(256) void scatter_add(const float* __restrict__ feat,
                                                   const int* __restrict__ src,
                                                   const int* __restrict__ dst,
                                                   float* __restrict__ agg, int E) {
    const int D = 4 << LOGP;
    long long tid = (long long)blockIdx.x * 256 + threadIdx.x;
    long long total = (long long)E << LOGP;
    if (tid >= total) return;
    int e = (int)(tid >> LOGP);
    int f = (int)(tid & ((1 << LOGP) - 1)) * 4;
    int s = src[e];
    int d = dst[e];
    const float4 v = *(const float4*)&feat[(long long)s * D + f];
    float* p = &agg[(long long)d * D + f];
    atomicAdd(p + 0, v.x);
    atomicAdd(p + 1, v.y);
    atomicAdd(p + 2, v.z);
    atomicAdd(p + 3, v.w);
}

// ---------------- fused SAGE layer GEMM ----------------
// out[n,o] = act( sum_k inv[n]*Aagg[n,k]*Wl[o,k] + bias[o] + sum_k Aself[n,k]*Wr[o,k] )
// A: [N,K] row-major; W: [O,K] row-major (so both are K-contiguous "NT" gemm).
#define BM 64
#define BN 64
#define BK 32

template <int K, bool RELU>
__global__ __launch_bounds__(256) void sage_gemm(const float* __restrict__ Aagg,
                                                 const float* __restrict__ inv,
                                                 const float* __restrict__ Aself,
                                                 const float* __restrict__ Wl,
                                                 const float* __restrict__ bias,
                                                 const float* __restrict__ Wr,
                                                 float* __restrict__ out, int N, int O) {
    // transposed tiles: [k][m] so the compute loop does contiguous float4 reads
    __shared__ float As[BK][BM + 4];
    __shared__ float Bs[BK][BN + 4];

    const int tid = threadIdx.x;
    const int bm0 = blockIdx.x * BM;
    const int bn0 = blockIdx.y * BN;
    const int tx = tid & 15;   // col micro-tile (4 cols)
    const int ty = tid >> 4;   // row micro-tile (4 rows)
    const int lr = tid >> 3;        // loader row 0..31
    const int lc4 = (tid & 7) * 4;  // loader col offset 0,4,...,28

    float c[4][4] = {};

    for (int phase = 0; phase < 2; ++phase) {
        const float* __restrict__ A = phase ? Aself : Aagg;
        const float* __restrict__ W = phase ? Wr : Wl;
        for (int kk = 0; kk < K; kk += BK) {
            // ---- load A tile (64 rows x 32 cols), scale agg rows by inv ----
#pragma unroll
            for (int h = 0; h < 2; ++h) {
                int m = lr + h * 32;
                int row = bm0 + m;
                float4 v = make_float4(0.f, 0.f, 0.f, 0.f);
                if (row < N) {
                    v = *(const float4*)&A[(long long)row * K + kk + lc4];
                    if (phase == 0) {
                        float s = inv[row];
                        v.x *= s; v.y *= s; v.z *= s; v.w *= s;
                    }
                }
                As[lc4 + 0][m] = v.x;
                As[lc4 + 1][m] = v.y;
                As[lc4 + 2][m] = v.z;
                As[lc4 + 3][m] = v.w;
            }
            // ---- load B tile (64 out-cols x 32 k) ----
#pragma unroll
            for (int h = 0; h < 2; ++h) {
                int o = lr + h * 32;
                int orow = bn0 + o;
                float4 v = make_float4(0.f, 0.f, 0.f, 0.f);
                if (orow < O) v = *(const float4*)&W[(long long)orow * K + kk + lc4];
                Bs[lc4 + 0][o] = v.x;
                Bs[lc4 + 1][o] = v.y;
                Bs[lc4 + 2][o] = v.z;
                Bs[lc4 + 3][o] = v.w;
            }
            __syncthreads();
#pragma unroll
            for (int k = 0; k < BK; ++k) {
                float4 a = *(const float4*)&As[k][ty * 4];
                float4 b = *(const float4*)&Bs[k][tx * 4];
                float av[4] = {a.x, a.y, a.z, a.w};
                float bv[4] = {b.x, b.y, b.z, b.w};
#pragma unroll
                for (int i = 0; i < 4; ++i)
#pragma unroll
                    for (int j = 0; j < 4; ++j) c[i][j] += av[i] * bv[j];
            }
            __syncthreads();
        }
    }

    // ---- epilogue: bias + activation + store ----
#pragma unroll
    for (int i = 0; i < 4; ++i) {
        int row = bm0 + ty * 4 + i;
        if (row >= N) continue;
#pragma unroll
        for (int j = 0; j < 4; ++j) {
            int o = bn0 + tx * 4 + j;
            if (o >= O) continue;
            float v = c[i][j] + bias[o];
            if (RELU) v = fmaxf(v, 0.f);
            out[(long long)row * O + o] = v;
        }
    }
}

// ---------------- log_softmax over 40 cols, one wave per row ----------------
__global__ __launch_bounds__(256) void log_softmax40(const float* __restrict__ h,
                                                     float* __restrict__ out, int N) {
    int wave = threadIdx.x >> 6;
    int lane = threadIdx.x & 63;
    int row = blockIdx.x * 4 + wave;
    if (row >= N) return;
    float v = (lane < OUT_DIM) ? h[(long long)row * OUT_DIM + lane] : -INFINITY;
    float m = v;
#pragma unroll
    for (int o = 32; o > 0; o >>= 1) m = fmaxf(m, __shfl_xor(m, o, 64));
    float e = (lane < OUT_DIM) ? expf(v - m) : 0.f;
    float s = e;
#pragma unroll
    for (int o = 32; o > 0; o >>= 1) s += __shfl_xor(s, o, 64);
    float ls = logf(s);
    if (lane < OUT_DIM) out[(long long)row * OUT_DIM + lane] = v - m - ls;
}

extern "C" void kernel_launch(void* const* d_in, const int* in_sizes, int n_in,
                              void* d_out, int out_size, void* d_ws, size_t ws_size,
                              hipStream_t stream) {
    const float* x   = (const float*)d_in[0];
    const int*   ei  = (const int*)d_in[1];
    const float* Wl1 = (const float*)d_in[2];
    const float* bl1 = (const float*)d_in[3];
    const float* Wr1 = (const float*)d_in[4];
    const float* Wl2 = (const float*)d_in[5];
    const float* bl2 = (const float*)d_in[6];
    const float* Wr2 = (const float*)d_in[7];
    const float* Wl3 = (const float*)d_in[8];
    const float* bl3 = (const float*)d_in[9];
    const float* Wr3 = (const float*)d_in[10];
    float* out = (float*)d_out;

    const int N = in_sizes[0] / N_NODES_IN_DIM;  // 50000
    const int E = in_sizes[1] / 2;               // 600000
    const int* src = ei;
    const int* dst = ei + E;

    // workspace layout
    float* B0  = (float*)d_ws;             // agg/mean buffer [N,256]
    float* B1  = B0 + (size_t)N * HID_DIM; // h1 / h3
    float* B2  = B1 + (size_t)N * HID_DIM; // h2
    float* cnt = B2 + (size_t)N * HID_DIM;
    float* inv = cnt + ((N + 63) & ~63);

    // ---- degree counts (shared across layers) ----
    hipMemsetAsync(cnt, 0, (size_t)N * sizeof(float), stream);
    count_edges<<<(E + 255) / 256, 256, 0, stream>>>(dst, cnt, E);
    recip_cnt<<<(N + 255) / 256, 256, 0, stream>>>(cnt, inv, N);

    const int gm = (N + BM - 1) / BM;  // 782

    // ---- layer 1: K=128, O=256, relu ----
    hipMemsetAsync(B0, 0, (size_t)N * N_NODES_IN_DIM * sizeof(float), stream);
    {
        long long total = (long long)E << 5;  // D=128 -> 32 float4 per edge
        scatter_add<5><<<(int)((total + 255) / 256), 256, 0, stream>>>(x, src, dst, B0, E);
    }
    sage_gemm<128, true><<<dim3(gm, HID_DIM / BN), 256, 0, stream>>>(
        B0, inv, x, Wl1, bl1, Wr1, B1, N, HID_DIM);

    // ---- layer 2: K=256, O=256, relu ----
    hipMemsetAsync(B0, 0, (size_t)N * HID_DIM * sizeof(float), stream);
    {
        long long total = (long long)E << 6;  // D=256 -> 64 float4 per edge
        scatter_add<6><<<(int)((total + 255) / 256), 256, 0, stream>>>(B1, src, dst, B0, E);
    }
    sage_gemm<256, true><<<dim3(gm, HID_DIM / BN), 256, 0, stream>>>(
        B0, inv, B1, Wl2, bl2, Wr2, B2, N, HID_DIM);

    // ---- layer 3: K=256, O=40, no relu; h3 -> B1 (reuse) ----
    hipMemsetAsync(B0, 0, (size_t)N * HID_DIM * sizeof(float), stream);
    {
        long long total = (long long)E << 6;
        scatter_add<6><<<(int)((total + 255) / 256), 256, 0, stream>>>(B2, src, dst, B0, E);
    }
    sage_gemm<256, false><<<dim3(gm, 1), 256, 0, stream>>>(
        B0, inv, B2, Wl3, bl3, Wr3, B1, N, OUT_DIM);

    // ---- log_softmax ----
    log_softmax40<<<(N + 3) / 4, 256, 0, stream>>>(B1, out, N);
}

// Round 2
// 858.685 us; speedup vs baseline: 6.4470x; 6.4470x over previous
//
#include <hip/hip_runtime.h>
#include <hip/hip_bf16.h>

#define IN_DIM 128
#define HID_DIM 256
#define OUT_DIM 40

// ---------------- CSR build ----------------
__global__ __launch_bounds__(256) void hist_kernel(const int* __restrict__ dst,
                                                   int* __restrict__ cnt, int E) {
    int e = blockIdx.x * 256 + threadIdx.x;
    if (e < E) atomicAdd(&cnt[dst[e]], 1);
}

// single block, 1024 threads: exclusive scan of cnt -> rowptr & cursor, plus inv = 1/max(cnt,1)
__global__ __launch_bounds__(1024) void scan_kernel(const int* __restrict__ cnt,
                                                    int* __restrict__ rowptr,
                                                    int* __restrict__ cursor,
                                                    float* __restrict__ inv, int N, int E) {
    __shared__ int ls[1024];
    const int t = threadIdx.x;
    const int CH = (N + 1023) >> 10;
    const int base = t * CH;
    const int lim = min(base + CH, N);
    int s = 0;
    for (int i = base; i < lim; ++i) s += cnt[i];
    ls[t] = s;
    __syncthreads();
    for (int off = 1; off < 1024; off <<= 1) {
        int v = (t >= off) ? ls[t - off] : 0;
        __syncthreads();
        ls[t] += v;
        __syncthreads();
    }
    int run = ls[t] - s;  // exclusive prefix
    for (int i = base; i < lim; ++i) {
        int c = cnt[i];
        rowptr[i] = run;
        cursor[i] = run;
        inv[i] = 1.0f / fmaxf((float)c, 1.0f);
        run += c;
    }
    if (t == 0) rowptr[N] = E;
}

__global__ __launch_bounds__(256) void fill_kernel(const int* __restrict__ src,
                                                   const int* __restrict__ dst,
                                                   int* __restrict__ cursor,
                                                   int* __restrict__ srcs, int E) {
    int e = blockIdx.x * 256 + threadIdx.x;
    if (e < E) {
        int pos = atomicAdd(&cursor[dst[e]], 1);
        srcs[pos] = src[e];
    }
}

// ---------------- gather mean: one wave per dst node ----------------
template <int D>
__global__ __launch_bounds__(256) void gather_mean(const float* __restrict__ feat,
                                                   const int* __restrict__ rowptr,
                                                   const int* __restrict__ srcs,
                                                   const float* __restrict__ inv,
                                                   float* __restrict__ out, int N) {
    constexpr int V = D / 64;  // floats per lane
    const int wave = threadIdx.x >> 6;
    const int lane = threadIdx.x & 63;
    const int n = blockIdx.x * 4 + wave;
    if (n >= N) return;
    const int beg = rowptr[n];
    const int end = rowptr[n + 1];
    const int col = lane * V;
    float acc[V] = {};
    int e = beg;
    // 2-wide manual unroll for load-latency overlap
    for (; e + 1 < end; e += 2) {
        int s0 = srcs[e], s1 = srcs[e + 1];
        const float* p0 = &feat[(long long)s0 * D + col];
        const float* p1 = &feat[(long long)s1 * D + col];
        if constexpr (V == 4) {
            float4 a = *(const float4*)p0;
            float4 b = *(const float4*)p1;
            acc[0] += a.x + b.x; acc[1] += a.y + b.y;
            acc[2] += a.z + b.z; acc[3] += a.w + b.w;
        } else {
            float2 a = *(const float2*)p0;
            float2 b = *(const float2*)p1;
            acc[0] += a.x + b.x; acc[1] += a.y + b.y;
        }
    }
    if (e < end) {
        int s0 = srcs[e];
        const float* p0 = &feat[(long long)s0 * D + col];
        if constexpr (V == 4) {
            float4 a = *(const float4*)p0;
            acc[0] += a.x; acc[1] += a.y; acc[2] += a.z; acc[3] += a.w;
        } else {
            float2 a = *(const float2*)p0;
            acc[0] += a.x; acc[1] += a.y;
        }
    }
    const float sc = inv[n];
    float* po = &out[(long long)n * D + col];
    if constexpr (V == 4) {
        *(float4*)po = make_float4(acc[0] * sc, acc[1] * sc, acc[2] * sc, acc[3] * sc);
    } else {
        *(float2*)po = make_float2(acc[0] * sc, acc[1] * sc);
    }
}

// ---------------- fused SAGE layer GEMM ----------------
// out[n,o] = act( sum_k Amean[n,k]*Wl[o,k] + bias[o] + sum_k Aself[n,k]*Wr[o,k] )
#define BM 64
#define BN 64
#define BK 32

template <int K, bool RELU>
__global__ __launch_bounds__(256) void sage_gemm(const float* __restrict__ Amean,
                                                 const float* __restrict__ Aself,
                                                 const float* __restrict__ Wl,
                                                 const float* __restrict__ bias,
                                                 const float* __restrict__ Wr,
                                                 float* __restrict__ out, int N, int O) {
    __shared__ float As[BK][BM + 4];
    __shared__ float Bs[BK][BN + 4];

    const int tid = threadIdx.x;
    const int bm0 = blockIdx.x * BM;
    const int bn0 = blockIdx.y * BN;
    const int tx = tid & 15;
    const int ty = tid >> 4;
    const int lr = tid >> 3;
    const int lc4 = (tid & 7) * 4;

    float c[4][4] = {};

    for (int phase = 0; phase < 2; ++phase) {
        const float* __restrict__ A = phase ? Aself : Amean;
        const float* __restrict__ W = phase ? Wr : Wl;
        for (int kk = 0; kk < K; kk += BK) {
#pragma unroll
            for (int h = 0; h < 2; ++h) {
                int m = lr + h * 32;
                int row = bm0 + m;
                float4 v = make_float4(0.f, 0.f, 0.f, 0.f);
                if (row < N) v = *(const float4*)&A[(long long)row * K + kk + lc4];
                As[lc4 + 0][m] = v.x;
                As[lc4 + 1][m] = v.y;
                As[lc4 + 2][m] = v.z;
                As[lc4 + 3][m] = v.w;
            }
#pragma unroll
            for (int h = 0; h < 2; ++h) {
                int o = lr + h * 32;
                int orow = bn0 + o;
                float4 v = make_float4(0.f, 0.f, 0.f, 0.f);
                if (orow < O) v = *(const float4*)&W[(long long)orow * K + kk + lc4];
                Bs[lc4 + 0][o] = v.x;
                Bs[lc4 + 1][o] = v.y;
                Bs[lc4 + 2][o] = v.z;
                Bs[lc4 + 3][o] = v.w;
            }
            __syncthreads();
#pragma unroll
            for (int k = 0; k < BK; ++k) {
                float4 a = *(const float4*)&As[k][ty * 4];
                float4 b = *(const float4*)&Bs[k][tx * 4];
                float av[4] = {a.x, a.y, a.z, a.w};
                float bv[4] = {b.x, b.y, b.z, b.w};
#pragma unroll
                for (int i = 0; i < 4; ++i)
#pragma unroll
                    for (int j = 0; j < 4; ++j) c[i][j] += av[i] * bv[j];
            }
            __syncthreads();
        }
    }

#pragma unroll
    for (int i = 0; i < 4; ++i) {
        int row = bm0 + ty * 4 + i;
        if (row >= N) continue;
#pragma unroll
        for (int j = 0; j < 4; ++j) {
            int o = bn0 + tx * 4 + j;
            if (o >= O) continue;
            float v = c[i][j] + bias[o];
            if (RELU) v = fmaxf(v, 0.f);
            out[(long long)row * O + o] = v;
        }
    }
}

// ---------------- log_softmax over 40 cols, one wave per row ----------------
__global__ __launch_bounds__(256) void log_softmax40(const float* __restrict__ h,
                                                     float* __restrict__ out, int N) {
    int wave = threadIdx.x >> 6;
    int lane = threadIdx.x & 63;
    int row = blockIdx.x * 4 + wave;
    if (row >= N) return;
    float v = (lane < OUT_DIM) ? h[(long long)row * OUT_DIM + lane] : -INFINITY;
    float m = v;
#pragma unroll
    for (int o = 32; o > 0; o >>= 1) m = fmaxf(m, __shfl_xor(m, o, 64));
    float e = (lane < OUT_DIM) ? expf(v - m) : 0.f;
    float s = e;
#pragma unroll
    for (int o = 32; o > 0; o >>= 1) s += __shfl_xor(s, o, 64);
    float ls = logf(s);
    if (lane < OUT_DIM) out[(long long)row * OUT_DIM + lane] = v - m - ls;
}

extern "C" void kernel_launch(void* const* d_in, const int* in_sizes, int n_in,
                              void* d_out, int out_size, void* d_ws, size_t ws_size,
                              hipStream_t stream) {
    const float* x   = (const float*)d_in[0];
    const int*   ei  = (const int*)d_in[1];
    const float* Wl1 = (const float*)d_in[2];
    const float* bl1 = (const float*)d_in[3];
    const float* Wr1 = (const float*)d_in[4];
    const float* Wl2 = (const float*)d_in[5];
    const float* bl2 = (const float*)d_in[6];
    const float* Wr2 = (const float*)d_in[7];
    const float* Wl3 = (const float*)d_in[8];
    const float* bl3 = (const float*)d_in[9];
    const float* Wr3 = (const float*)d_in[10];
    float* out = (float*)d_out;

    const int N = in_sizes[0] / IN_DIM;  // 50000
    const int E = in_sizes[1] / 2;       // 600000
    const int* src = ei;
    const int* dst = ei + E;

    // workspace layout
    float* B0     = (float*)d_ws;              // mean buffer [N,256]
    float* B1     = B0 + (size_t)N * HID_DIM;  // h1 / h3
    float* B2     = B1 + (size_t)N * HID_DIM;  // h2
    float* inv    = B2 + (size_t)N * HID_DIM;
    int*   cnt    = (int*)(inv + ((N + 63) & ~63));
    int*   rowptr = cnt + ((N + 63) & ~63);
    int*   cursor = rowptr + ((N + 1 + 63) & ~63);
    int*   srcs   = cursor + ((N + 63) & ~63);  // [E]

    // ---- CSR build (shared across the 3 layers) ----
    hipMemsetAsync(cnt, 0, (size_t)N * sizeof(int), stream);
    hist_kernel<<<(E + 255) / 256, 256, 0, stream>>>(dst, cnt, E);
    scan_kernel<<<1, 1024, 0, stream>>>(cnt, rowptr, cursor, inv, N, E);
    fill_kernel<<<(E + 255) / 256, 256, 0, stream>>>(src, dst, cursor, srcs, E);

    const int gm = (N + BM - 1) / BM;
    const int gg = (N + 3) / 4;

    // ---- layer 1: K=128, O=256, relu ----
    gather_mean<IN_DIM><<<gg, 256, 0, stream>>>(x, rowptr, srcs, inv, B0, N);
    sage_gemm<IN_DIM, true><<<dim3(gm, HID_DIM / BN), 256, 0, stream>>>(
        B0, x, Wl1, bl1, Wr1, B1, N, HID_DIM);

    // ---- layer 2: K=256, O=256, relu ----
    gather_mean<HID_DIM><<<gg, 256, 0, stream>>>(B1, rowptr, srcs, inv, B0, N);
    sage_gemm<HID_DIM, true><<<dim3(gm, HID_DIM / BN), 256, 0, stream>>>(
        B0, B1, Wl2, bl2, Wr2, B2, N, HID_DIM);

    // ---- layer 3: K=256, O=40, no relu; h3 -> B1 (reuse) ----
    gather_mean<HID_DIM><<<gg, 256, 0, stream>>>(B2, rowptr, srcs, inv, B0, N);
    sage_gemm<HID_DIM, false><<<dim3(gm, 1), 256, 0, stream>>>(
        B0, B2, Wl3, bl3, Wr3, B1, N, OUT_DIM);

    // ---- log_softmax ----
    log_softmax40<<<gg, 256, 0, stream>>>(B1, out, N);
}

// Round 3
// 620.232 us; speedup vs baseline: 8.9256x; 1.3845x over previous
//
#include <hip/hip_runtime.h>
#include <hip/hip_bf16.h>

#define IN_DIM 128
#define HID_DIM 256
#define OUT_DIM 40

typedef __attribute__((ext_vector_type(8))) __bf16 bf16x8;
typedef __attribute__((ext_vector_type(4))) float f32x4;

__device__ inline ushort f2bf(float f) {
    uint u = __builtin_bit_cast(uint, f);
    u = (u + 0x7fff + ((u >> 16) & 1)) >> 16;
    return (ushort)u;
}
__device__ inline float bfl(uint u) { return __builtin_bit_cast(float, u << 16); }
__device__ inline float bfh(uint u) { return __builtin_bit_cast(float, u & 0xffff0000u); }

// ---------------- input/weight conversion ----------------
__global__ __launch_bounds__(256) void cvt_x(const float* __restrict__ in,
                                             ushort* __restrict__ out, int n4) {
    int i = blockIdx.x * 256 + threadIdx.x;
    if (i < n4) {
        float4 v = ((const float4*)in)[i];
        uint2 o;
        o.x = (uint)f2bf(v.x) | ((uint)f2bf(v.y) << 16);
        o.y = (uint)f2bf(v.z) | ((uint)f2bf(v.w) << 16);
        ((uint2*)out)[i] = o;
    }
}

// convert+pad a layer's two weight mats [O][K] fp32 -> [OPAD][K] bf16 (zero pad)
__global__ __launch_bounds__(256) void cvt_w2(const float* __restrict__ wl,
                                              const float* __restrict__ wr,
                                              ushort* __restrict__ ol,
                                              ushort* __restrict__ orr,
                                              int O, int OPAD, int K) {
    int idx = blockIdx.x * 256 + threadIdx.x;
    int tot = OPAD * K;
    if (idx >= tot) return;
    int row = idx / K;
    int col = idx - row * K;
    ushort vl = 0, vr = 0;
    if (row < O) {
        vl = f2bf(wl[row * K + col]);
        vr = f2bf(wr[row * K + col]);
    }
    ol[idx] = vl;
    orr[idx] = vr;
}

// ---------------- CSR build ----------------
__global__ __launch_bounds__(256) void hist_kernel(const int* __restrict__ dst,
                                                   int* __restrict__ cnt, int E) {
    int e = blockIdx.x * 256 + threadIdx.x;
    if (e < E) atomicAdd(&cnt[dst[e]], 1);
}

__global__ __launch_bounds__(1024) void scan_kernel(const int* __restrict__ cnt,
                                                    int* __restrict__ rowptr,
                                                    int* __restrict__ cursor,
                                                    float* __restrict__ inv, int N, int E) {
    __shared__ int ls[1024];
    const int t = threadIdx.x;
    const int CH = (N + 1023) >> 10;
    const int base = t * CH;
    const int lim = min(base + CH, N);
    int s = 0;
    for (int i = base; i < lim; ++i) s += cnt[i];
    ls[t] = s;
    __syncthreads();
    for (int off = 1; off < 1024; off <<= 1) {
        int v = (t >= off) ? ls[t - off] : 0;
        __syncthreads();
        ls[t] += v;
        __syncthreads();
    }
    int run = ls[t] - s;
    for (int i = base; i < lim; ++i) {
        int c = cnt[i];
        rowptr[i] = run;
        cursor[i] = run;
        inv[i] = 1.0f / fmaxf((float)c, 1.0f);
        run += c;
    }
    if (t == 0) rowptr[N] = E;
}

__global__ __launch_bounds__(256) void fill_kernel(const int* __restrict__ src,
                                                   const int* __restrict__ dst,
                                                   int* __restrict__ cursor,
                                                   int* __restrict__ srcs, int E) {
    int e = blockIdx.x * 256 + threadIdx.x;
    if (e < E) {
        int pos = atomicAdd(&cursor[dst[e]], 1);
        srcs[pos] = src[e];
    }
}

// ---------------- gather mean (bf16 in/out, fp32 accumulate) ----------------
template <int D>
__global__ __launch_bounds__(256) void gather_mean_bf(const ushort* __restrict__ feat,
                                                      const int* __restrict__ rowptr,
                                                      const int* __restrict__ srcs,
                                                      const float* __restrict__ inv,
                                                      ushort* __restrict__ out, int N) {
    constexpr int V = D / 64;  // bf16 per lane: 2 or 4
    const int wave = threadIdx.x >> 6;
    const int lane = threadIdx.x & 63;
    const int n = blockIdx.x * 4 + wave;
    if (n >= N) return;
    const int beg = rowptr[n];
    const int end = rowptr[n + 1];
    const int col = lane * V;
    float a0 = 0.f, a1 = 0.f, a2 = 0.f, a3 = 0.f;
    int e = beg;
    for (; e + 1 < end; e += 2) {
        int s0 = srcs[e], s1 = srcs[e + 1];
        if constexpr (V == 4) {
            uint2 q0 = *(const uint2*)&feat[(long long)s0 * D + col];
            uint2 q1 = *(const uint2*)&feat[(long long)s1 * D + col];
            a0 += bfl(q0.x) + bfl(q1.x);
            a1 += bfh(q0.x) + bfh(q1.x);
            a2 += bfl(q0.y) + bfl(q1.y);
            a3 += bfh(q0.y) + bfh(q1.y);
        } else {
            uint q0 = *(const uint*)&feat[(long long)s0 * D + col];
            uint q1 = *(const uint*)&feat[(long long)s1 * D + col];
            a0 += bfl(q0) + bfl(q1);
            a1 += bfh(q0) + bfh(q1);
        }
    }
    if (e < end) {
        int s0 = srcs[e];
        if constexpr (V == 4) {
            uint2 q0 = *(const uint2*)&feat[(long long)s0 * D + col];
            a0 += bfl(q0.x); a1 += bfh(q0.x); a2 += bfl(q0.y); a3 += bfh(q0.y);
        } else {
            uint q0 = *(const uint*)&feat[(long long)s0 * D + col];
            a0 += bfl(q0); a1 += bfh(q0);
        }
    }
    const float sc = inv[n];
    if constexpr (V == 4) {
        uint2 o;
        o.x = (uint)f2bf(a0 * sc) | ((uint)f2bf(a1 * sc) << 16);
        o.y = (uint)f2bf(a2 * sc) | ((uint)f2bf(a3 * sc) << 16);
        *(uint2*)&out[(long long)n * D + col] = o;
    } else {
        uint o = (uint)f2bf(a0 * sc) | ((uint)f2bf(a1 * sc) << 16);
        *(uint*)&out[(long long)n * D + col] = o;
    }
}

// ---------------- MFMA SAGE GEMM ----------------
// out[m][o] = act( sum_k Amean[m][k]*Wl[o][k] + bias[o] + sum_k Aself[m][k]*Wr[o][k] )
// A: bf16 [N][K]; W: bf16 [OPAD][K] (zero-padded). Block: 128 rows x 64 cols, 4 waves.
// Wave w: rows w*32..w*32+31 (2 row-tiles of 16), all 4 col-tiles of 16.
template <int K, int OPAD, bool RELU, bool OUTBF>
__global__ __launch_bounds__(256) void sage_gemm_mfma(const ushort* __restrict__ Amean,
                                                      const ushort* __restrict__ Aself,
                                                      const ushort* __restrict__ Wl,
                                                      const float* __restrict__ bias,
                                                      const ushort* __restrict__ Wr,
                                                      void* __restrict__ outv, int N, int O) {
    __shared__ __align__(16) ushort At[128 * 32];  // [row][k], 8 KB
    const int tid = threadIdx.x;
    const int wave = tid >> 6;
    const int lane = tid & 63;
    const int ln = lane & 15;
    const int quad = lane >> 4;
    const int bm0 = blockIdx.x * 128;
    const int bn0 = blockIdx.y * 64;

    f32x4 acc[2][4] = {};

    for (int phase = 0; phase < 2; ++phase) {
        const ushort* __restrict__ A = phase ? Aself : Amean;
        const ushort* __restrict__ W = phase ? Wr : Wl;
#pragma unroll 2
        for (int kk = 0; kk < K; kk += 32) {
            __syncthreads();  // protect At against previous iter's readers
            // stage A tile: 128 rows x 32 k, 16B per thread x2
#pragma unroll
            for (int i = 0; i < 2; ++i) {
                int t = i * 256 + tid;   // 0..511
                int row = t >> 2;        // 0..127
                int c8 = (t & 3) * 8;    // k offset 0,8,16,24
                ulonglong2 v;
                v.x = 0; v.y = 0;
                int grow = bm0 + row;
                if (grow < N) v = *(const ulonglong2*)&A[(long long)grow * K + kk + c8];
                *(ulonglong2*)&At[t * 8] = v;
            }
            __syncthreads();
            // A fragments from LDS
            bf16x8 a[2];
#pragma unroll
            for (int rt = 0; rt < 2; ++rt) {
                int r = wave * 32 + rt * 16 + ln;
                a[rt] = *(const bf16x8*)&At[r * 32 + quad * 8];
            }
            // B fragments straight from global (weights are L1/L2-resident)
#pragma unroll
            for (int ct = 0; ct < 4; ++ct) {
                int n = bn0 + ct * 16 + ln;
                bf16x8 b = *(const bf16x8*)&W[(long long)n * K + kk + quad * 8];
#pragma unroll
                for (int rt = 0; rt < 2; ++rt)
                    acc[rt][ct] = __builtin_amdgcn_mfma_f32_16x16x32_bf16(a[rt], b, acc[rt][ct], 0, 0, 0);
            }
        }
    }

    // epilogue: C/D layout col=lane&15, row=quad*4+reg
#pragma unroll
    for (int rt = 0; rt < 2; ++rt) {
        int rbase = bm0 + wave * 32 + rt * 16 + quad * 4;
#pragma unroll
        for (int ct = 0; ct < 4; ++ct) {
            int col = bn0 + ct * 16 + ln;
            if (col >= O) continue;
            float bv = bias[col];
#pragma unroll
            for (int r = 0; r < 4; ++r) {
                int row = rbase + r;
                if (row >= N) continue;
                float v = acc[rt][ct][r] + bv;
                if (RELU) v = fmaxf(v, 0.f);
                if (OUTBF)
                    ((ushort*)outv)[(long long)row * O + col] = f2bf(v);
                else
                    ((float*)outv)[(long long)row * O + col] = v;
            }
        }
    }
}

// ---------------- log_softmax over 40 cols, one wave per row ----------------
__global__ __launch_bounds__(256) void log_softmax40(const float* __restrict__ h,
                                                     float* __restrict__ out, int N) {
    int wave = threadIdx.x >> 6;
    int lane = threadIdx.x & 63;
    int row = blockIdx.x * 4 + wave;
    if (row >= N) return;
    float v = (lane < OUT_DIM) ? h[(long long)row * OUT_DIM + lane] : -INFINITY;
    float m = v;
#pragma unroll
    for (int o = 32; o > 0; o >>= 1) m = fmaxf(m, __shfl_xor(m, o, 64));
    float e = (lane < OUT_DIM) ? expf(v - m) : 0.f;
    float s = e;
#pragma unroll
    for (int o = 32; o > 0; o >>= 1) s += __shfl_xor(s, o, 64);
    float ls = logf(s);
    if (lane < OUT_DIM) out[(long long)row * OUT_DIM + lane] = v - m - ls;
}

extern "C" void kernel_launch(void* const* d_in, const int* in_sizes, int n_in,
                              void* d_out, int out_size, void* d_ws, size_t ws_size,
                              hipStream_t stream) {
    const float* x   = (const float*)d_in[0];
    const int*   ei  = (const int*)d_in[1];
    const float* Wl1 = (const float*)d_in[2];
    const float* bl1 = (const float*)d_in[3];
    const float* Wr1 = (const float*)d_in[4];
    const float* Wl2 = (const float*)d_in[5];
    const float* bl2 = (const float*)d_in[6];
    const float* Wr2 = (const float*)d_in[7];
    const float* Wl3 = (const float*)d_in[8];
    const float* bl3 = (const float*)d_in[9];
    const float* Wr3 = (const float*)d_in[10];
    float* out = (float*)d_out;

    const int N = in_sizes[0] / IN_DIM;  // 50000
    const int E = in_sizes[1] / 2;       // 600000
    const int* src = ei;
    const int* dst = ei + E;

    // ---- workspace layout (256B aligned chunks) ----
    char* w = (char*)d_ws;
    size_t off = 0;
    auto alloc = [&](size_t bytes) {
        void* p = w + off;
        off = (off + bytes + 255) & ~(size_t)255;
        return p;
    };
    ushort* xb   = (ushort*)alloc((size_t)N * IN_DIM * 2);
    ushort* M    = (ushort*)alloc((size_t)N * HID_DIM * 2);   // mean buffer
    ushort* H1   = (ushort*)alloc((size_t)N * HID_DIM * 2);
    ushort* H2   = (ushort*)alloc((size_t)N * HID_DIM * 2);
    float*  H3   = (float*)alloc((size_t)N * OUT_DIM * 4);
    float*  inv  = (float*)alloc((size_t)N * 4);
    int*    cnt  = (int*)alloc((size_t)N * 4);
    int*    rowptr = (int*)alloc((size_t)(N + 1) * 4);
    int*    cursor = (int*)alloc((size_t)N * 4);
    int*    srcs = (int*)alloc((size_t)E * 4);
    ushort* Wl1b = (ushort*)alloc(256 * 128 * 2);
    ushort* Wr1b = (ushort*)alloc(256 * 128 * 2);
    ushort* Wl2b = (ushort*)alloc(256 * 256 * 2);
    ushort* Wr2b = (ushort*)alloc(256 * 256 * 2);
    ushort* Wl3b = (ushort*)alloc(64 * 256 * 2);
    ushort* Wr3b = (ushort*)alloc(64 * 256 * 2);

    // ---- conversions ----
    cvt_x<<<(N * IN_DIM / 4 + 255) / 256, 256, 0, stream>>>(x, xb, N * IN_DIM / 4);
    cvt_w2<<<(256 * 128 + 255) / 256, 256, 0, stream>>>(Wl1, Wr1, Wl1b, Wr1b, 256, 256, 128);
    cvt_w2<<<(256 * 256 + 255) / 256, 256, 0, stream>>>(Wl2, Wr2, Wl2b, Wr2b, 256, 256, 256);
    cvt_w2<<<(64 * 256 + 255) / 256, 256, 0, stream>>>(Wl3, Wr3, Wl3b, Wr3b, 40, 64, 256);

    // ---- CSR build ----
    hipMemsetAsync(cnt, 0, (size_t)N * sizeof(int), stream);
    hist_kernel<<<(E + 255) / 256, 256, 0, stream>>>(dst, cnt, E);
    scan_kernel<<<1, 1024, 0, stream>>>(cnt, rowptr, cursor, inv, N, E);
    fill_kernel<<<(E + 255) / 256, 256, 0, stream>>>(src, dst, cursor, srcs, E);

    const int gm = (N + 127) / 128;  // 391
    const int gg = (N + 3) / 4;

    // ---- layer 1: K=128 -> 256, relu ----
    gather_mean_bf<IN_DIM><<<gg, 256, 0, stream>>>(xb, rowptr, srcs, inv, M, N);
    sage_gemm_mfma<IN_DIM, 256, true, true><<<dim3(gm, 4), 256, 0, stream>>>(
        M, xb, Wl1b, bl1, Wr1b, H1, N, HID_DIM);

    // ---- layer 2: K=256 -> 256, relu ----
    gather_mean_bf<HID_DIM><<<gg, 256, 0, stream>>>(H1, rowptr, srcs, inv, M, N);
    sage_gemm_mfma<HID_DIM, 256, true, true><<<dim3(gm, 4), 256, 0, stream>>>(
        M, H1, Wl2b, bl2, Wr2b, H2, N, HID_DIM);

    // ---- layer 3: K=256 -> 40, no relu, fp32 out ----
    gather_mean_bf<HID_DIM><<<gg, 256, 0, stream>>>(H2, rowptr, srcs, inv, M, N);
    sage_gemm_mfma<HID_DIM, 64, false, false><<<dim3(gm, 1), 256, 0, stream>>>(
        M, H2, Wl3b, bl3, Wr3b, H3, N, OUT_DIM);

    // ---- log_softmax ----
    log_softmax40<<<gg, 256, 0, stream>>>(H3, out, N);
}

// Round 4
// 501.116 us; speedup vs baseline: 11.0472x; 1.2377x over previous
//
#include <hip/hip_runtime.h>
#include <hip/hip_bf16.h>

#define IN_DIM 128
#define HID_DIM 256
#define OUT_DIM 40
#define SCAN_CHUNK 2048

typedef __attribute__((ext_vector_type(8))) __bf16 bf16x8;
typedef __attribute__((ext_vector_type(4))) float f32x4;

__device__ inline ushort f2bf(float f) {
    uint u = __builtin_bit_cast(uint, f);
    u = (u + 0x7fff + ((u >> 16) & 1)) >> 16;
    return (ushort)u;
}
__device__ inline float bfl(uint u) { return __builtin_bit_cast(float, u << 16); }
__device__ inline float bfh(uint u) { return __builtin_bit_cast(float, u & 0xffff0000u); }

// ---------------- input/weight conversion ----------------
__global__ __launch_bounds__(256) void cvt_x(const float* __restrict__ in,
                                             ushort* __restrict__ out, int n4) {
    int i = blockIdx.x * 256 + threadIdx.x;
    if (i < n4) {
        float4 v = ((const float4*)in)[i];
        uint2 o;
        o.x = (uint)f2bf(v.x) | ((uint)f2bf(v.y) << 16);
        o.y = (uint)f2bf(v.z) | ((uint)f2bf(v.w) << 16);
        ((uint2*)out)[i] = o;
    }
}

// convert+pad a layer's two weight mats [O][K] fp32 -> [OPAD][K] bf16 (zero pad)
__global__ __launch_bounds__(256) void cvt_w2(const float* __restrict__ wl,
                                              const float* __restrict__ wr,
                                              ushort* __restrict__ ol,
                                              ushort* __restrict__ orr,
                                              int O, int OPAD, int K) {
    int idx = blockIdx.x * 256 + threadIdx.x;
    int tot = OPAD * K;
    if (idx >= tot) return;
    int row = idx / K;
    int col = idx - row * K;
    ushort vl = 0, vr = 0;
    if (row < O) {
        vl = f2bf(wl[row * K + col]);
        vr = f2bf(wr[row * K + col]);
    }
    ol[idx] = vl;
    orr[idx] = vr;
}

// ---------------- CSR build ----------------
__global__ __launch_bounds__(256) void hist_kernel(const int* __restrict__ dst,
                                                   int* __restrict__ cnt, int E) {
    int e = blockIdx.x * 256 + threadIdx.x;
    if (e < E) atomicAdd(&cnt[dst[e]], 1);
}

// pass1: per-block partial sums over SCAN_CHUNK elements
__global__ __launch_bounds__(256) void scan_pass1(const int* __restrict__ cnt,
                                                  int* __restrict__ bsum, int N) {
    __shared__ int red[256];
    const int base = blockIdx.x * SCAN_CHUNK;
    int s = 0;
    for (int i = threadIdx.x; i < SCAN_CHUNK; i += 256) {
        int idx = base + i;
        if (idx < N) s += cnt[idx];
    }
    red[threadIdx.x] = s;
    __syncthreads();
    for (int o = 128; o > 0; o >>= 1) {
        if (threadIdx.x < o) red[threadIdx.x] += red[threadIdx.x + o];
        __syncthreads();
    }
    if (threadIdx.x == 0) bsum[blockIdx.x] = red[0];
}

// pass2: single small block exclusive-scans the block sums (B <= 256)
__global__ __launch_bounds__(256) void scan_pass2(int* __restrict__ bsum, int B) {
    __shared__ int ls[256];
    const int t = threadIdx.x;
    int v = (t < B) ? bsum[t] : 0;
    ls[t] = v;
    __syncthreads();
    for (int o = 1; o < 256; o <<= 1) {
        int u = (t >= o) ? ls[t - o] : 0;
        __syncthreads();
        ls[t] += u;
        __syncthreads();
    }
    if (t < B) bsum[t] = ls[t] - v;  // exclusive
}

// pass3: local LDS scan (8 elems/thread) + block offset -> rowptr/cursor/inv
__global__ __launch_bounds__(256) void scan_pass3(const int* __restrict__ cnt,
                                                  const int* __restrict__ bsum,
                                                  int* __restrict__ rowptr,
                                                  int* __restrict__ cursor,
                                                  float* __restrict__ inv, int N, int E) {
    __shared__ int ls[256];
    const int tbase = blockIdx.x * SCAN_CHUNK + threadIdx.x * 8;
    int c[8];
    int s = 0;
#pragma unroll
    for (int j = 0; j < 8; ++j) {
        int idx = tbase + j;
        c[j] = (idx < N) ? cnt[idx] : 0;
        s += c[j];
    }
    ls[threadIdx.x] = s;
    __syncthreads();
    for (int o = 1; o < 256; o <<= 1) {
        int u = (threadIdx.x >= o) ? ls[threadIdx.x - o] : 0;
        __syncthreads();
        ls[threadIdx.x] += u;
        __syncthreads();
    }
    int run = bsum[blockIdx.x] + ls[threadIdx.x] - s;
#pragma unroll
    for (int j = 0; j < 8; ++j) {
        int idx = tbase + j;
        if (idx < N) {
            rowptr[idx] = run;
            cursor[idx] = run;
            inv[idx] = 1.0f / fmaxf((float)c[j], 1.0f);
            run += c[j];
        }
    }
    if (blockIdx.x == 0 && threadIdx.x == 0) rowptr[N] = E;
}

__global__ __launch_bounds__(256) void fill_kernel(const int* __restrict__ src,
                                                   const int* __restrict__ dst,
                                                   int* __restrict__ cursor,
                                                   int* __restrict__ srcs, int E) {
    int e = blockIdx.x * 256 + threadIdx.x;
    if (e < E) {
        int pos = atomicAdd(&cursor[dst[e]], 1);
        srcs[pos] = src[e];
    }
}

// ---------------- gather mean (bf16 in/out, fp32 accumulate) ----------------
template <int D>
__global__ __launch_bounds__(256) void gather_mean_bf(const ushort* __restrict__ feat,
                                                      const int* __restrict__ rowptr,
                                                      const int* __restrict__ srcs,
                                                      const float* __restrict__ inv,
                                                      ushort* __restrict__ out, int N) {
    constexpr int V = D / 64;  // bf16 per lane: 2 or 4
    const int wave = threadIdx.x >> 6;
    const int lane = threadIdx.x & 63;
    const int n = blockIdx.x * 4 + wave;
    if (n >= N) return;
    const int beg = rowptr[n];
    const int end = rowptr[n + 1];
    const int col = lane * V;
    float a0 = 0.f, a1 = 0.f, a2 = 0.f, a3 = 0.f;
    int e = beg;
    for (; e + 1 < end; e += 2) {
        int s0 = srcs[e], s1 = srcs[e + 1];
        if constexpr (V == 4) {
            uint2 q0 = *(const uint2*)&feat[(long long)s0 * D + col];
            uint2 q1 = *(const uint2*)&feat[(long long)s1 * D + col];
            a0 += bfl(q0.x) + bfl(q1.x);
            a1 += bfh(q0.x) + bfh(q1.x);
            a2 += bfl(q0.y) + bfl(q1.y);
            a3 += bfh(q0.y) + bfh(q1.y);
        } else {
            uint q0 = *(const uint*)&feat[(long long)s0 * D + col];
            uint q1 = *(const uint*)&feat[(long long)s1 * D + col];
            a0 += bfl(q0) + bfl(q1);
            a1 += bfh(q0) + bfh(q1);
        }
    }
    if (e < end) {
        int s0 = srcs[e];
        if constexpr (V == 4) {
            uint2 q0 = *(const uint2*)&feat[(long long)s0 * D + col];
            a0 += bfl(q0.x); a1 += bfh(q0.x); a2 += bfl(q0.y); a3 += bfh(q0.y);
        } else {
            uint q0 = *(const uint*)&feat[(long long)s0 * D + col];
            a0 += bfl(q0); a1 += bfh(q0);
        }
    }
    const float sc = inv[n];
    if constexpr (V == 4) {
        uint2 o;
        o.x = (uint)f2bf(a0 * sc) | ((uint)f2bf(a1 * sc) << 16);
        o.y = (uint)f2bf(a2 * sc) | ((uint)f2bf(a3 * sc) << 16);
        *(uint2*)&out[(long long)n * D + col] = o;
    } else {
        uint o = (uint)f2bf(a0 * sc) | ((uint)f2bf(a1 * sc) << 16);
        *(uint*)&out[(long long)n * D + col] = o;
    }
}

// ---------------- MFMA SAGE GEMM ----------------
// out[m][o] = act( sum_k Amean[m][k]*Wl[o][k] + bias[o] + sum_k Aself[m][k]*Wr[o][k] )
// A: bf16 [N][K]; W: bf16 [OPAD][K] (zero-padded). Block: 128 rows x 64 cols, 4 waves.
template <int K, int OPAD, bool RELU, bool OUTBF>
__global__ __launch_bounds__(256) void sage_gemm_mfma(const ushort* __restrict__ Amean,
                                                      const ushort* __restrict__ Aself,
                                                      const ushort* __restrict__ Wl,
                                                      const float* __restrict__ bias,
                                                      const ushort* __restrict__ Wr,
                                                      void* __restrict__ outv, int N, int O) {
    __shared__ __align__(16) ushort At[128 * 32];  // [row][k], 8 KB
    const int tid = threadIdx.x;
    const int wave = tid >> 6;
    const int lane = tid & 63;
    const int ln = lane & 15;
    const int quad = lane >> 4;
    const int bm0 = blockIdx.x * 128;
    const int bn0 = blockIdx.y * 64;

    f32x4 acc[2][4] = {};

    for (int phase = 0; phase < 2; ++phase) {
        const ushort* __restrict__ A = phase ? Aself : Amean;
        const ushort* __restrict__ W = phase ? Wr : Wl;
#pragma unroll 2
        for (int kk = 0; kk < K; kk += 32) {
            __syncthreads();
#pragma unroll
            for (int i = 0; i < 2; ++i) {
                int t = i * 256 + tid;
                int row = t >> 2;
                int c8 = (t & 3) * 8;
                ulonglong2 v;
                v.x = 0; v.y = 0;
                int grow = bm0 + row;
                if (grow < N) v = *(const ulonglong2*)&A[(long long)grow * K + kk + c8];
                *(ulonglong2*)&At[t * 8] = v;
            }
            __syncthreads();
            bf16x8 a[2];
#pragma unroll
            for (int rt = 0; rt < 2; ++rt) {
                int r = wave * 32 + rt * 16 + ln;
                a[rt] = *(const bf16x8*)&At[r * 32 + quad * 8];
            }
#pragma unroll
            for (int ct = 0; ct < 4; ++ct) {
                int n = bn0 + ct * 16 + ln;
                bf16x8 b = *(const bf16x8*)&W[(long long)n * K + kk + quad * 8];
#pragma unroll
                for (int rt = 0; rt < 2; ++rt)
                    acc[rt][ct] = __builtin_amdgcn_mfma_f32_16x16x32_bf16(a[rt], b, acc[rt][ct], 0, 0, 0);
            }
        }
    }

#pragma unroll
    for (int rt = 0; rt < 2; ++rt) {
        int rbase = bm0 + wave * 32 + rt * 16 + quad * 4;
#pragma unroll
        for (int ct = 0; ct < 4; ++ct) {
            int col = bn0 + ct * 16 + ln;
            if (col >= O) continue;
            float bv = bias[col];
#pragma unroll
            for (int r = 0; r < 4; ++r) {
                int row = rbase + r;
                if (row >= N) continue;
                float v = acc[rt][ct][r] + bv;
                if (RELU) v = fmaxf(v, 0.f);
                if (OUTBF)
                    ((ushort*)outv)[(long long)row * O + col] = f2bf(v);
                else
                    ((float*)outv)[(long long)row * O + col] = v;
            }
        }
    }
}

// ---------------- log_softmax over 40 cols, one wave per row ----------------
__global__ __launch_bounds__(256) void log_softmax40(const float* __restrict__ h,
                                                     float* __restrict__ out, int N) {
    int wave = threadIdx.x >> 6;
    int lane = threadIdx.x & 63;
    int row = blockIdx.x * 4 + wave;
    if (row >= N) return;
    float v = (lane < OUT_DIM) ? h[(long long)row * OUT_DIM + lane] : -INFINITY;
    float m = v;
#pragma unroll
    for (int o = 32; o > 0; o >>= 1) m = fmaxf(m, __shfl_xor(m, o, 64));
    float e = (lane < OUT_DIM) ? expf(v - m) : 0.f;
    float s = e;
#pragma unroll
    for (int o = 32; o > 0; o >>= 1) s += __shfl_xor(s, o, 64);
    float ls = logf(s);
    if (lane < OUT_DIM) out[(long long)row * OUT_DIM + lane] = v - m - ls;
}

extern "C" void kernel_launch(void* const* d_in, const int* in_sizes, int n_in,
                              void* d_out, int out_size, void* d_ws, size_t ws_size,
                              hipStream_t stream) {
    const float* x   = (const float*)d_in[0];
    const int*   ei  = (const int*)d_in[1];
    const float* Wl1 = (const float*)d_in[2];
    const float* bl1 = (const float*)d_in[3];
    const float* Wr1 = (const float*)d_in[4];
    const float* Wl2 = (const float*)d_in[5];
    const float* bl2 = (const float*)d_in[6];
    const float* Wr2 = (const float*)d_in[7];
    const float* Wl3 = (const float*)d_in[8];
    const float* bl3 = (const float*)d_in[9];
    const float* Wr3 = (const float*)d_in[10];
    float* out = (float*)d_out;

    const int N = in_sizes[0] / IN_DIM;  // 50000
    const int E = in_sizes[1] / 2;       // 600000
    const int* src = ei;
    const int* dst = ei + E;

    // ---- workspace layout ----
    char* w = (char*)d_ws;
    size_t off = 0;
    auto alloc = [&](size_t bytes) {
        void* p = w + off;
        off = (off + bytes + 255) & ~(size_t)255;
        return p;
    };
    ushort* xb   = (ushort*)alloc((size_t)N * IN_DIM * 2);
    ushort* M    = (ushort*)alloc((size_t)N * HID_DIM * 2);
    ushort* H1   = (ushort*)alloc((size_t)N * HID_DIM * 2);
    ushort* H2   = (ushort*)alloc((size_t)N * HID_DIM * 2);
    float*  H3   = (float*)alloc((size_t)N * OUT_DIM * 4);
    float*  inv  = (float*)alloc((size_t)N * 4);
    int*    cnt  = (int*)alloc((size_t)N * 4);
    int*    rowptr = (int*)alloc((size_t)(N + 1) * 4);
    int*    cursor = (int*)alloc((size_t)N * 4);
    int*    srcs = (int*)alloc((size_t)E * 4);
    int*    bsum = (int*)alloc(256 * 4);
    ushort* Wl1b = (ushort*)alloc(256 * 128 * 2);
    ushort* Wr1b = (ushort*)alloc(256 * 128 * 2);
    ushort* Wl2b = (ushort*)alloc(256 * 256 * 2);
    ushort* Wr2b = (ushort*)alloc(256 * 256 * 2);
    ushort* Wl3b = (ushort*)alloc(64 * 256 * 2);
    ushort* Wr3b = (ushort*)alloc(64 * 256 * 2);

    // ---- conversions ----
    cvt_x<<<(N * IN_DIM / 4 + 255) / 256, 256, 0, stream>>>(x, xb, N * IN_DIM / 4);
    cvt_w2<<<(256 * 128 + 255) / 256, 256, 0, stream>>>(Wl1, Wr1, Wl1b, Wr1b, 256, 256, 128);
    cvt_w2<<<(256 * 256 + 255) / 256, 256, 0, stream>>>(Wl2, Wr2, Wl2b, Wr2b, 256, 256, 256);
    cvt_w2<<<(64 * 256 + 255) / 256, 256, 0, stream>>>(Wl3, Wr3, Wl3b, Wr3b, 40, 64, 256);

    // ---- CSR build (parallel 3-pass scan) ----
    const int SB = (N + SCAN_CHUNK - 1) / SCAN_CHUNK;  // 25
    hipMemsetAsync(cnt, 0, (size_t)N * sizeof(int), stream);
    hist_kernel<<<(E + 255) / 256, 256, 0, stream>>>(dst, cnt, E);
    scan_pass1<<<SB, 256, 0, stream>>>(cnt, bsum, N);
    scan_pass2<<<1, 256, 0, stream>>>(bsum, SB);
    scan_pass3<<<SB, 256, 0, stream>>>(cnt, bsum, rowptr, cursor, inv, N, E);
    fill_kernel<<<(E + 255) / 256, 256, 0, stream>>>(src, dst, cursor, srcs, E);

    const int gm = (N + 127) / 128;  // 391
    const int gg = (N + 3) / 4;

    // ---- layer 1: K=128 -> 256, relu ----
    gather_mean_bf<IN_DIM><<<gg, 256, 0, stream>>>(xb, rowptr, srcs, inv, M, N);
    sage_gemm_mfma<IN_DIM, 256, true, true><<<dim3(gm, 4), 256, 0, stream>>>(
        M, xb, Wl1b, bl1, Wr1b, H1, N, HID_DIM);

    // ---- layer 2: K=256 -> 256, relu ----
    gather_mean_bf<HID_DIM><<<gg, 256, 0, stream>>>(H1, rowptr, srcs, inv, M, N);
    sage_gemm_mfma<HID_DIM, 256, true, true><<<dim3(gm, 4), 256, 0, stream>>>(
        M, H1, Wl2b, bl2, Wr2b, H2, N, HID_DIM);

    // ---- layer 3: K=256 -> 40, no relu, fp32 out ----
    gather_mean_bf<HID_DIM><<<gg, 256, 0, stream>>>(H2, rowptr, srcs, inv, M, N);
    sage_gemm_mfma<HID_DIM, 64, false, false><<<dim3(gm, 1), 256, 0, stream>>>(
        M, H2, Wl3b, bl3, Wr3b, H3, N, OUT_DIM);

    // ---- log_softmax ----
    log_softmax40<<<gg, 256, 0, stream>>>(H3, out, N);
}

// Round 5
// 433.788 us; speedup vs baseline: 12.7619x; 1.1552x over previous
//
#include <hip/hip_runtime.h>
#include <hip/hip_bf16.h>

#define IN_DIM 128
#define HID_DIM 256
#define OUT_DIM 40
#define SCAN_CHUNK 2048

typedef __attribute__((ext_vector_type(8))) __bf16 bf16x8;
typedef __attribute__((ext_vector_type(4))) float f32x4;

__device__ inline ushort f2bf(float f) {
    uint u = __builtin_bit_cast(uint, f);
    u = (u + 0x7fff + ((u >> 16) & 1)) >> 16;
    return (ushort)u;
}
__device__ inline float bfl(uint u) { return __builtin_bit_cast(float, u << 16); }
__device__ inline float bfh(uint u) { return __builtin_bit_cast(float, u & 0xffff0000u); }

// ---------------- input/weight conversion ----------------
__global__ __launch_bounds__(256) void cvt_x(const float* __restrict__ in,
                                             ushort* __restrict__ out, int n4) {
    int i = blockIdx.x * 256 + threadIdx.x;
    if (i < n4) {
        float4 v = ((const float4*)in)[i];
        uint2 o;
        o.x = (uint)f2bf(v.x) | ((uint)f2bf(v.y) << 16);
        o.y = (uint)f2bf(v.z) | ((uint)f2bf(v.w) << 16);
        ((uint2*)out)[i] = o;
    }
}

// convert+pad a layer's two weight mats [O][K] fp32 -> [OPAD][K] bf16 (zero pad)
__global__ __launch_bounds__(256) void cvt_w2(const float* __restrict__ wl,
                                              const float* __restrict__ wr,
                                              ushort* __restrict__ ol,
                                              ushort* __restrict__ orr,
                                              int O, int OPAD, int K) {
    int idx = blockIdx.x * 256 + threadIdx.x;
    int tot = OPAD * K;
    if (idx >= tot) return;
    int row = idx / K;
    int col = idx - row * K;
    ushort vl = 0, vr = 0;
    if (row < O) {
        vl = f2bf(wl[row * K + col]);
        vr = f2bf(wr[row * K + col]);
    }
    ol[idx] = vl;
    orr[idx] = vr;
}

// ---------------- CSR build ----------------
__global__ __launch_bounds__(256) void hist_kernel(const int* __restrict__ dst,
                                                   int* __restrict__ cnt, int E) {
    int e = blockIdx.x * 256 + threadIdx.x;
    if (e < E) atomicAdd(&cnt[dst[e]], 1);
}

__global__ __launch_bounds__(256) void scan_pass1(const int* __restrict__ cnt,
                                                  int* __restrict__ bsum, int N) {
    __shared__ int red[256];
    const int base = blockIdx.x * SCAN_CHUNK;
    int s = 0;
    for (int i = threadIdx.x; i < SCAN_CHUNK; i += 256) {
        int idx = base + i;
        if (idx < N) s += cnt[idx];
    }
    red[threadIdx.x] = s;
    __syncthreads();
    for (int o = 128; o > 0; o >>= 1) {
        if (threadIdx.x < o) red[threadIdx.x] += red[threadIdx.x + o];
        __syncthreads();
    }
    if (threadIdx.x == 0) bsum[blockIdx.x] = red[0];
}

__global__ __launch_bounds__(256) void scan_pass2(int* __restrict__ bsum, int B) {
    __shared__ int ls[256];
    const int t = threadIdx.x;
    int v = (t < B) ? bsum[t] : 0;
    ls[t] = v;
    __syncthreads();
    for (int o = 1; o < 256; o <<= 1) {
        int u = (t >= o) ? ls[t - o] : 0;
        __syncthreads();
        ls[t] += u;
        __syncthreads();
    }
    if (t < B) bsum[t] = ls[t] - v;  // exclusive
}

__global__ __launch_bounds__(256) void scan_pass3(const int* __restrict__ cnt,
                                                  const int* __restrict__ bsum,
                                                  int* __restrict__ rowptr,
                                                  int* __restrict__ cursor,
                                                  float* __restrict__ inv, int N, int E) {
    __shared__ int ls[256];
    const int tbase = blockIdx.x * SCAN_CHUNK + threadIdx.x * 8;
    int c[8];
    int s = 0;
#pragma unroll
    for (int j = 0; j < 8; ++j) {
        int idx = tbase + j;
        c[j] = (idx < N) ? cnt[idx] : 0;
        s += c[j];
    }
    ls[threadIdx.x] = s;
    __syncthreads();
    for (int o = 1; o < 256; o <<= 1) {
        int u = (threadIdx.x >= o) ? ls[threadIdx.x - o] : 0;
        __syncthreads();
        ls[threadIdx.x] += u;
        __syncthreads();
    }
    int run = bsum[blockIdx.x] + ls[threadIdx.x] - s;
#pragma unroll
    for (int j = 0; j < 8; ++j) {
        int idx = tbase + j;
        if (idx < N) {
            rowptr[idx] = run;
            cursor[idx] = run;
            inv[idx] = 1.0f / fmaxf((float)c[j], 1.0f);
            run += c[j];
        }
    }
    if (blockIdx.x == 0 && threadIdx.x == 0) rowptr[N] = E;
}

__global__ __launch_bounds__(256) void fill_kernel(const int* __restrict__ src,
                                                   const int* __restrict__ dst,
                                                   int* __restrict__ cursor,
                                                   int* __restrict__ srcs, int E) {
    int e = blockIdx.x * 256 + threadIdx.x;
    if (e < E) {
        int pos = atomicAdd(&cursor[dst[e]], 1);
        srcs[pos] = src[e];
    }
}

// ---------------- gather mean (bf16 in/out, fp32 accumulate) ----------------
template <int D>
__global__ __launch_bounds__(256) void gather_mean_bf(const ushort* __restrict__ feat,
                                                      const int* __restrict__ rowptr,
                                                      const int* __restrict__ srcs,
                                                      const float* __restrict__ inv,
                                                      ushort* __restrict__ out, int N) {
    constexpr int V = D / 64;  // bf16 per lane: 2 or 4
    const int wave = threadIdx.x >> 6;
    const int lane = threadIdx.x & 63;
    const int n = blockIdx.x * 4 + wave;
    if (n >= N) return;
    const int beg = rowptr[n];
    const int end = rowptr[n + 1];
    const int col = lane * V;
    float a0 = 0.f, a1 = 0.f, a2 = 0.f, a3 = 0.f;
    int e = beg;
    for (; e + 1 < end; e += 2) {
        int s0 = srcs[e], s1 = srcs[e + 1];
        if constexpr (V == 4) {
            uint2 q0 = *(const uint2*)&feat[(long long)s0 * D + col];
            uint2 q1 = *(const uint2*)&feat[(long long)s1 * D + col];
            a0 += bfl(q0.x) + bfl(q1.x);
            a1 += bfh(q0.x) + bfh(q1.x);
            a2 += bfl(q0.y) + bfl(q1.y);
            a3 += bfh(q0.y) + bfh(q1.y);
        } else {
            uint q0 = *(const uint*)&feat[(long long)s0 * D + col];
            uint q1 = *(const uint*)&feat[(long long)s1 * D + col];
            a0 += bfl(q0) + bfl(q1);
            a1 += bfh(q0) + bfh(q1);
        }
    }
    if (e < end) {
        int s0 = srcs[e];
        if constexpr (V == 4) {
            uint2 q0 = *(const uint2*)&feat[(long long)s0 * D + col];
            a0 += bfl(q0.x); a1 += bfh(q0.x); a2 += bfl(q0.y); a3 += bfh(q0.y);
        } else {
            uint q0 = *(const uint*)&feat[(long long)s0 * D + col];
            a0 += bfl(q0); a1 += bfh(q0);
        }
    }
    const float sc = inv[n];
    if constexpr (V == 4) {
        uint2 o;
        o.x = (uint)f2bf(a0 * sc) | ((uint)f2bf(a1 * sc) << 16);
        o.y = (uint)f2bf(a2 * sc) | ((uint)f2bf(a3 * sc) << 16);
        *(uint2*)&out[(long long)n * D + col] = o;
    } else {
        uint o = (uint)f2bf(a0 * sc) | ((uint)f2bf(a1 * sc) << 16);
        *(uint*)&out[(long long)n * D + col] = o;
    }
}

// ---------------- MFMA SAGE GEMM (v2: W in LDS, A direct from global) ----------------
// out[m][o] = act( sum_k Amean[m][k]*Wl[o][k] + bias[o] + sum_k Aself[m][k]*Wr[o][k] )
// Block: 128 rows x 64 cols, 4 waves. W tile staged in LDS once per phase
// (padded +8 bf16/row -> conflict-free ds_read_b128); A fragments are 8
// contiguous bf16 per lane, loaded straight from global (L2/L3-resident),
// so the K-loop has no barriers.
template <int K, int OPAD, bool RELU, bool OUTBF>
__global__ __launch_bounds__(256, 4) void sage_gemm_mfma(const ushort* __restrict__ Amean,
                                                         const ushort* __restrict__ Aself,
                                                         const ushort* __restrict__ Wl,
                                                         const float* __restrict__ bias,
                                                         const ushort* __restrict__ Wr,
                                                         void* __restrict__ outv, int N, int O) {
    constexpr int KP = K + 8;  // padded LDS row (bank-conflict-free)
    __shared__ __align__(16) ushort Bs[64 * KP];

    const int tid = threadIdx.x;
    const int wave = tid >> 6;
    const int lane = tid & 63;
    const int ln = lane & 15;
    const int quad = lane >> 4;
    const int bm0 = blockIdx.x * 128;
    const int bn0 = blockIdx.y * 64;

    // this wave's two A-row indices (clamped; OOB rows discarded in epilogue)
    int arow[2];
#pragma unroll
    for (int rt = 0; rt < 2; ++rt) {
        int r = bm0 + wave * 32 + rt * 16 + ln;
        arow[rt] = min(r, N - 1);
    }

    f32x4 acc[2][4] = {};

    for (int phase = 0; phase < 2; ++phase) {
        const ushort* __restrict__ A = phase ? Aself : Amean;
        const ushort* __restrict__ W = phase ? Wr : Wl;

        __syncthreads();  // protect Bs against previous phase's readers
        // stage W tile: 64 cols x K, 16B chunks, fully coalesced
#pragma unroll
        for (int i = tid; i < 64 * (K / 8); i += 256) {
            int row = i / (K / 8);
            int c8 = (i % (K / 8)) * 8;
            *(ulonglong2*)&Bs[row * KP + c8] =
                *(const ulonglong2*)&W[(long long)(bn0 + row) * K + c8];
        }
        __syncthreads();

        // barrier-free K loop
#pragma unroll
        for (int kk = 0; kk < K; kk += 32) {
            bf16x8 a[2];
#pragma unroll
            for (int rt = 0; rt < 2; ++rt)
                a[rt] = *(const bf16x8*)&A[(long long)arow[rt] * K + kk + quad * 8];
#pragma unroll
            for (int ct = 0; ct < 4; ++ct) {
                bf16x8 b = *(const bf16x8*)&Bs[(ct * 16 + ln) * KP + kk + quad * 8];
#pragma unroll
                for (int rt = 0; rt < 2; ++rt)
                    acc[rt][ct] = __builtin_amdgcn_mfma_f32_16x16x32_bf16(a[rt], b, acc[rt][ct], 0, 0, 0);
            }
        }
    }

    // epilogue: C/D layout col=lane&15, row=quad*4+reg
#pragma unroll
    for (int rt = 0; rt < 2; ++rt) {
        int rbase = bm0 + wave * 32 + rt * 16 + quad * 4;
#pragma unroll
        for (int ct = 0; ct < 4; ++ct) {
            int col = bn0 + ct * 16 + ln;
            if (col >= O) continue;
            float bv = bias[col];
#pragma unroll
            for (int r = 0; r < 4; ++r) {
                int row = rbase + r;
                if (row >= N) continue;
                float v = acc[rt][ct][r] + bv;
                if (RELU) v = fmaxf(v, 0.f);
                if (OUTBF)
                    ((ushort*)outv)[(long long)row * O + col] = f2bf(v);
                else
                    ((float*)outv)[(long long)row * O + col] = v;
            }
        }
    }
}

// ---------------- log_softmax over 40 cols, one wave per row ----------------
__global__ __launch_bounds__(256) void log_softmax40(const float* __restrict__ h,
                                                     float* __restrict__ out, int N) {
    int wave = threadIdx.x >> 6;
    int lane = threadIdx.x & 63;
    int row = blockIdx.x * 4 + wave;
    if (row >= N) return;
    float v = (lane < OUT_DIM) ? h[(long long)row * OUT_DIM + lane] : -INFINITY;
    float m = v;
#pragma unroll
    for (int o = 32; o > 0; o >>= 1) m = fmaxf(m, __shfl_xor(m, o, 64));
    float e = (lane < OUT_DIM) ? expf(v - m) : 0.f;
    float s = e;
#pragma unroll
    for (int o = 32; o > 0; o >>= 1) s += __shfl_xor(s, o, 64);
    float ls = logf(s);
    if (lane < OUT_DIM) out[(long long)row * OUT_DIM + lane] = v - m - ls;
}

extern "C" void kernel_launch(void* const* d_in, const int* in_sizes, int n_in,
                              void* d_out, int out_size, void* d_ws, size_t ws_size,
                              hipStream_t stream) {
    const float* x   = (const float*)d_in[0];
    const int*   ei  = (const int*)d_in[1];
    const float* Wl1 = (const float*)d_in[2];
    const float* bl1 = (const float*)d_in[3];
    const float* Wr1 = (const float*)d_in[4];
    const float* Wl2 = (const float*)d_in[5];
    const float* bl2 = (const float*)d_in[6];
    const float* Wr2 = (const float*)d_in[7];
    const float* Wl3 = (const float*)d_in[8];
    const float* bl3 = (const float*)d_in[9];
    const float* Wr3 = (const float*)d_in[10];
    float* out = (float*)d_out;

    const int N = in_sizes[0] / IN_DIM;  // 50000
    const int E = in_sizes[1] / 2;       // 600000
    const int* src = ei;
    const int* dst = ei + E;

    // ---- workspace layout ----
    char* w = (char*)d_ws;
    size_t off = 0;
    auto alloc = [&](size_t bytes) {
        void* p = w + off;
        off = (off + bytes + 255) & ~(size_t)255;
        return p;
    };
    ushort* xb   = (ushort*)alloc((size_t)N * IN_DIM * 2);
    ushort* M    = (ushort*)alloc((size_t)N * HID_DIM * 2);
    ushort* H1   = (ushort*)alloc((size_t)N * HID_DIM * 2);
    ushort* H2   = (ushort*)alloc((size_t)N * HID_DIM * 2);
    float*  H3   = (float*)alloc((size_t)N * OUT_DIM * 4);
    float*  inv  = (float*)alloc((size_t)N * 4);
    int*    cnt  = (int*)alloc((size_t)N * 4);
    int*    rowptr = (int*)alloc((size_t)(N + 1) * 4);
    int*    cursor = (int*)alloc((size_t)N * 4);
    int*    srcs = (int*)alloc((size_t)E * 4);
    int*    bsum = (int*)alloc(256 * 4);
    ushort* Wl1b = (ushort*)alloc(256 * 128 * 2);
    ushort* Wr1b = (ushort*)alloc(256 * 128 * 2);
    ushort* Wl2b = (ushort*)alloc(256 * 256 * 2);
    ushort* Wr2b = (ushort*)alloc(256 * 256 * 2);
    ushort* Wl3b = (ushort*)alloc(64 * 256 * 2);
    ushort* Wr3b = (ushort*)alloc(64 * 256 * 2);

    // ---- conversions ----
    cvt_x<<<(N * IN_DIM / 4 + 255) / 256, 256, 0, stream>>>(x, xb, N * IN_DIM / 4);
    cvt_w2<<<(256 * 128 + 255) / 256, 256, 0, stream>>>(Wl1, Wr1, Wl1b, Wr1b, 256, 256, 128);
    cvt_w2<<<(256 * 256 + 255) / 256, 256, 0, stream>>>(Wl2, Wr2, Wl2b, Wr2b, 256, 256, 256);
    cvt_w2<<<(64 * 256 + 255) / 256, 256, 0, stream>>>(Wl3, Wr3, Wl3b, Wr3b, 40, 64, 256);

    // ---- CSR build (parallel 3-pass scan) ----
    const int SB = (N + SCAN_CHUNK - 1) / SCAN_CHUNK;  // 25
    hipMemsetAsync(cnt, 0, (size_t)N * sizeof(int), stream);
    hist_kernel<<<(E + 255) / 256, 256, 0, stream>>>(dst, cnt, E);
    scan_pass1<<<SB, 256, 0, stream>>>(cnt, bsum, N);
    scan_pass2<<<1, 256, 0, stream>>>(bsum, SB);
    scan_pass3<<<SB, 256, 0, stream>>>(cnt, bsum, rowptr, cursor, inv, N, E);
    fill_kernel<<<(E + 255) / 256, 256, 0, stream>>>(src, dst, cursor, srcs, E);

    const int gm = (N + 127) / 128;  // 391
    const int gg = (N + 3) / 4;

    // ---- layer 1: K=128 -> 256, relu ----
    gather_mean_bf<IN_DIM><<<gg, 256, 0, stream>>>(xb, rowptr, srcs, inv, M, N);
    sage_gemm_mfma<IN_DIM, 256, true, true><<<dim3(gm, 4), 256, 0, stream>>>(
        M, xb, Wl1b, bl1, Wr1b, H1, N, HID_DIM);

    // ---- layer 2: K=256 -> 256, relu ----
    gather_mean_bf<HID_DIM><<<gg, 256, 0, stream>>>(H1, rowptr, srcs, inv, M, N);
    sage_gemm_mfma<HID_DIM, 256, true, true><<<dim3(gm, 4), 256, 0, stream>>>(
        M, H1, Wl2b, bl2, Wr2b, H2, N, HID_DIM);

    // ---- layer 3: K=256 -> 40, no relu, fp32 out ----
    gather_mean_bf<HID_DIM><<<gg, 256, 0, stream>>>(H2, rowptr, srcs, inv, M, N);
    sage_gemm_mfma<HID_DIM, 64, false, false><<<dim3(gm, 1), 256, 0, stream>>>(
        M, H2, Wl3b, bl3, Wr3b, H3, N, OUT_DIM);

    // ---- log_softmax ----
    log_softmax40<<<gg, 256, 0, stream>>>(H3, out, N);
}

// Round 6
// 379.372 us; speedup vs baseline: 14.5924x; 1.1434x over previous
//
#include <hip/hip_runtime.h>
#include <hip/hip_bf16.h>

#define IN_DIM 128
#define HID_DIM 256
#define OUT_DIM 40
#define SCAN_CHUNK 2048

typedef __attribute__((ext_vector_type(8))) __bf16 bf16x8;
typedef __attribute__((ext_vector_type(4))) float f32x4;

__device__ inline ushort f2bf(float f) {
    uint u = __builtin_bit_cast(uint, f);
    u = (u + 0x7fff + ((u >> 16) & 1)) >> 16;
    return (ushort)u;
}
__device__ inline float bfl(uint u) { return __builtin_bit_cast(float, u << 16); }
__device__ inline float bfh(uint u) { return __builtin_bit_cast(float, u & 0xffff0000u); }

// ---------------- input/weight conversion ----------------
__global__ __launch_bounds__(256) void cvt_x(const float* __restrict__ in,
                                             ushort* __restrict__ out, int n4) {
    int i = blockIdx.x * 256 + threadIdx.x;
    if (i < n4) {
        float4 v = ((const float4*)in)[i];
        uint2 o;
        o.x = (uint)f2bf(v.x) | ((uint)f2bf(v.y) << 16);
        o.y = (uint)f2bf(v.z) | ((uint)f2bf(v.w) << 16);
        ((uint2*)out)[i] = o;
    }
}

__global__ __launch_bounds__(256) void cvt_w2(const float* __restrict__ wl,
                                              const float* __restrict__ wr,
                                              ushort* __restrict__ ol,
                                              ushort* __restrict__ orr,
                                              int O, int OPAD, int K) {
    int idx = blockIdx.x * 256 + threadIdx.x;
    int tot = OPAD * K;
    if (idx >= tot) return;
    int row = idx / K;
    int col = idx - row * K;
    ushort vl = 0, vr = 0;
    if (row < O) {
        vl = f2bf(wl[row * K + col]);
        vr = f2bf(wr[row * K + col]);
    }
    ol[idx] = vl;
    orr[idx] = vr;
}

// ---------------- CSR build ----------------
__global__ __launch_bounds__(256) void hist_kernel(const int* __restrict__ dst,
                                                   int* __restrict__ cnt, int E) {
    int e = blockIdx.x * 256 + threadIdx.x;
    if (e < E) atomicAdd(&cnt[dst[e]], 1);
}

__global__ __launch_bounds__(256) void scan_pass1(const int* __restrict__ cnt,
                                                  int* __restrict__ bsum, int N) {
    __shared__ int red[256];
    const int base = blockIdx.x * SCAN_CHUNK;
    int s = 0;
    for (int i = threadIdx.x; i < SCAN_CHUNK; i += 256) {
        int idx = base + i;
        if (idx < N) s += cnt[idx];
    }
    red[threadIdx.x] = s;
    __syncthreads();
    for (int o = 128; o > 0; o >>= 1) {
        if (threadIdx.x < o) red[threadIdx.x] += red[threadIdx.x + o];
        __syncthreads();
    }
    if (threadIdx.x == 0) bsum[blockIdx.x] = red[0];
}

__global__ __launch_bounds__(256) void scan_pass2(int* __restrict__ bsum, int B) {
    __shared__ int ls[256];
    const int t = threadIdx.x;
    int v = (t < B) ? bsum[t] : 0;
    ls[t] = v;
    __syncthreads();
    for (int o = 1; o < 256; o <<= 1) {
        int u = (t >= o) ? ls[t - o] : 0;
        __syncthreads();
        ls[t] += u;
        __syncthreads();
    }
    if (t < B) bsum[t] = ls[t] - v;  // exclusive
}

__global__ __launch_bounds__(256) void scan_pass3(const int* __restrict__ cnt,
                                                  const int* __restrict__ bsum,
                                                  int* __restrict__ rowptr,
                                                  int* __restrict__ cursor,
                                                  float* __restrict__ inv, int N, int E) {
    __shared__ int ls[256];
    const int tbase = blockIdx.x * SCAN_CHUNK + threadIdx.x * 8;
    int c[8];
    int s = 0;
#pragma unroll
    for (int j = 0; j < 8; ++j) {
        int idx = tbase + j;
        c[j] = (idx < N) ? cnt[idx] : 0;
        s += c[j];
    }
    ls[threadIdx.x] = s;
    __syncthreads();
    for (int o = 1; o < 256; o <<= 1) {
        int u = (threadIdx.x >= o) ? ls[threadIdx.x - o] : 0;
        __syncthreads();
        ls[threadIdx.x] += u;
        __syncthreads();
    }
    int run = bsum[blockIdx.x] + ls[threadIdx.x] - s;
#pragma unroll
    for (int j = 0; j < 8; ++j) {
        int idx = tbase + j;
        if (idx < N) {
            rowptr[idx] = run;
            cursor[idx] = run;
            inv[idx] = 1.0f / fmaxf((float)c[j], 1.0f);
            run += c[j];
        }
    }
    if (blockIdx.x == 0 && threadIdx.x == 0) rowptr[N] = E;
}

__global__ __launch_bounds__(256) void fill_kernel(const int* __restrict__ src,
                                                   const int* __restrict__ dst,
                                                   int* __restrict__ cursor,
                                                   int* __restrict__ srcs, int E) {
    int e = blockIdx.x * 256 + threadIdx.x;
    if (e < E) {
        int pos = atomicAdd(&cursor[dst[e]], 1);
        srcs[pos] = src[e];
    }
}

// ---------------- gather mean (bf16 in/out, fp32 accumulate, 4-wide ILP) ----------------
template <int D>
__global__ __launch_bounds__(256) void gather_mean_bf(const ushort* __restrict__ feat,
                                                      const int* __restrict__ rowptr,
                                                      const int* __restrict__ srcs,
                                                      const float* __restrict__ inv,
                                                      ushort* __restrict__ out, int N) {
    constexpr int V = D / 64;  // bf16 per lane: 2 or 4
    const int wave = threadIdx.x >> 6;
    const int lane = threadIdx.x & 63;
    const int n = blockIdx.x * 4 + wave;
    if (n >= N) return;
    const int beg = rowptr[n];
    const int end = rowptr[n + 1];
    const int col = lane * V;
    float a0 = 0.f, a1 = 0.f, a2 = 0.f, a3 = 0.f;
    int e = beg;
    if constexpr (V == 4) {
        for (; e + 3 < end; e += 4) {
            int s0 = srcs[e], s1 = srcs[e + 1], s2 = srcs[e + 2], s3 = srcs[e + 3];
            uint2 q0 = *(const uint2*)&feat[(long long)s0 * D + col];
            uint2 q1 = *(const uint2*)&feat[(long long)s1 * D + col];
            uint2 q2 = *(const uint2*)&feat[(long long)s2 * D + col];
            uint2 q3 = *(const uint2*)&feat[(long long)s3 * D + col];
            a0 += (bfl(q0.x) + bfl(q1.x)) + (bfl(q2.x) + bfl(q3.x));
            a1 += (bfh(q0.x) + bfh(q1.x)) + (bfh(q2.x) + bfh(q3.x));
            a2 += (bfl(q0.y) + bfl(q1.y)) + (bfl(q2.y) + bfl(q3.y));
            a3 += (bfh(q0.y) + bfh(q1.y)) + (bfh(q2.y) + bfh(q3.y));
        }
        for (; e + 1 < end; e += 2) {
            int s0 = srcs[e], s1 = srcs[e + 1];
            uint2 q0 = *(const uint2*)&feat[(long long)s0 * D + col];
            uint2 q1 = *(const uint2*)&feat[(long long)s1 * D + col];
            a0 += bfl(q0.x) + bfl(q1.x);
            a1 += bfh(q0.x) + bfh(q1.x);
            a2 += bfl(q0.y) + bfl(q1.y);
            a3 += bfh(q0.y) + bfh(q1.y);
        }
        if (e < end) {
            uint2 q0 = *(const uint2*)&feat[(long long)srcs[e] * D + col];
            a0 += bfl(q0.x); a1 += bfh(q0.x); a2 += bfl(q0.y); a3 += bfh(q0.y);
        }
        const float sc = inv[n];
        uint2 o;
        o.x = (uint)f2bf(a0 * sc) | ((uint)f2bf(a1 * sc) << 16);
        o.y = (uint)f2bf(a2 * sc) | ((uint)f2bf(a3 * sc) << 16);
        *(uint2*)&out[(long long)n * D + col] = o;
    } else {
        for (; e + 3 < end; e += 4) {
            int s0 = srcs[e], s1 = srcs[e + 1], s2 = srcs[e + 2], s3 = srcs[e + 3];
            uint q0 = *(const uint*)&feat[(long long)s0 * D + col];
            uint q1 = *(const uint*)&feat[(long long)s1 * D + col];
            uint q2 = *(const uint*)&feat[(long long)s2 * D + col];
            uint q3 = *(const uint*)&feat[(long long)s3 * D + col];
            a0 += (bfl(q0) + bfl(q1)) + (bfl(q2) + bfl(q3));
            a1 += (bfh(q0) + bfh(q1)) + (bfh(q2) + bfh(q3));
        }
        for (; e + 1 < end; e += 2) {
            int s0 = srcs[e], s1 = srcs[e + 1];
            uint q0 = *(const uint*)&feat[(long long)s0 * D + col];
            uint q1 = *(const uint*)&feat[(long long)s1 * D + col];
            a0 += bfl(q0) + bfl(q1);
            a1 += bfh(q0) + bfh(q1);
        }
        if (e < end) {
            uint q0 = *(const uint*)&feat[(long long)srcs[e] * D + col];
            a0 += bfl(q0); a1 += bfh(q0);
        }
        const float sc = inv[n];
        uint o = (uint)f2bf(a0 * sc) | ((uint)f2bf(a1 * sc) << 16);
        *(uint*)&out[(long long)n * D + col] = o;
    }
}

// ---------------- MFMA SAGE GEMM (W in LDS, A direct from global) ----------------
template <int K, bool RELU, bool OUTBF>
__global__ __launch_bounds__(256, 4) void sage_gemm_mfma(const ushort* __restrict__ Amean,
                                                         const ushort* __restrict__ Aself,
                                                         const ushort* __restrict__ Wl,
                                                         const float* __restrict__ bias,
                                                         const ushort* __restrict__ Wr,
                                                         void* __restrict__ outv, int N, int O) {
    constexpr int KP = K + 8;  // padded LDS row (bank-conflict-free)
    __shared__ __align__(16) ushort Bs[64 * KP];

    const int tid = threadIdx.x;
    const int wave = tid >> 6;
    const int lane = tid & 63;
    const int ln = lane & 15;
    const int quad = lane >> 4;
    const int bm0 = blockIdx.x * 128;
    const int bn0 = blockIdx.y * 64;

    int arow[2];
#pragma unroll
    for (int rt = 0; rt < 2; ++rt) {
        int r = bm0 + wave * 32 + rt * 16 + ln;
        arow[rt] = min(r, N - 1);
    }

    f32x4 acc[2][4] = {};

    for (int phase = 0; phase < 2; ++phase) {
        const ushort* __restrict__ A = phase ? Aself : Amean;
        const ushort* __restrict__ W = phase ? Wr : Wl;

        __syncthreads();
#pragma unroll
        for (int i = tid; i < 64 * (K / 8); i += 256) {
            int row = i / (K / 8);
            int c8 = (i % (K / 8)) * 8;
            *(ulonglong2*)&Bs[row * KP + c8] =
                *(const ulonglong2*)&W[(long long)(bn0 + row) * K + c8];
        }
        __syncthreads();

#pragma unroll
        for (int kk = 0; kk < K; kk += 32) {
            bf16x8 a[2];
#pragma unroll
            for (int rt = 0; rt < 2; ++rt)
                a[rt] = *(const bf16x8*)&A[(long long)arow[rt] * K + kk + quad * 8];
#pragma unroll
            for (int ct = 0; ct < 4; ++ct) {
                bf16x8 b = *(const bf16x8*)&Bs[(ct * 16 + ln) * KP + kk + quad * 8];
#pragma unroll
                for (int rt = 0; rt < 2; ++rt)
                    acc[rt][ct] = __builtin_amdgcn_mfma_f32_16x16x32_bf16(a[rt], b, acc[rt][ct], 0, 0, 0);
            }
        }
    }

#pragma unroll
    for (int rt = 0; rt < 2; ++rt) {
        int rbase = bm0 + wave * 32 + rt * 16 + quad * 4;
#pragma unroll
        for (int ct = 0; ct < 4; ++ct) {
            int col = bn0 + ct * 16 + ln;
            if (col >= O) continue;
            float bv = bias[col];
#pragma unroll
            for (int r = 0; r < 4; ++r) {
                int row = rbase + r;
                if (row >= N) continue;
                float v = acc[rt][ct][r] + bv;
                if (RELU) v = fmaxf(v, 0.f);
                if (OUTBF)
                    ((ushort*)outv)[(long long)row * O + col] = f2bf(v);
                else
                    ((float*)outv)[(long long)row * O + col] = v;
            }
        }
    }
}

// ---------------- layer-3 pre-aggregation GEMM: P = A@Wl^T (bf16), S = A@Wr^T (fp32) ----------------
// O = 40 (weights padded to 64 rows). mean_agg commutes with the linear map,
// so aggregation happens later on D=40 instead of D=256.
template <int K>
__global__ __launch_bounds__(256, 4) void sage_gemm_pre(const ushort* __restrict__ A0,
                                                        const ushort* __restrict__ Wl,
                                                        const ushort* __restrict__ Wr,
                                                        ushort* __restrict__ P,
                                                        float* __restrict__ S, int N, int O) {
    constexpr int KP = K + 8;
    __shared__ __align__(16) ushort Bs[64 * KP];

    const int tid = threadIdx.x;
    const int wave = tid >> 6;
    const int lane = tid & 63;
    const int ln = lane & 15;
    const int quad = lane >> 4;
    const int bm0 = blockIdx.x * 128;

    int arow[2];
#pragma unroll
    for (int rt = 0; rt < 2; ++rt) {
        int r = bm0 + wave * 32 + rt * 16 + ln;
        arow[rt] = min(r, N - 1);
    }

    for (int phase = 0; phase < 2; ++phase) {
        const ushort* __restrict__ W = phase ? Wr : Wl;

        __syncthreads();
#pragma unroll
        for (int i = tid; i < 64 * (K / 8); i += 256) {
            int row = i / (K / 8);
            int c8 = (i % (K / 8)) * 8;
            *(ulonglong2*)&Bs[row * KP + c8] =
                *(const ulonglong2*)&W[(long long)row * K + c8];
        }
        __syncthreads();

        f32x4 acc[2][4] = {};
#pragma unroll
        for (int kk = 0; kk < K; kk += 32) {
            bf16x8 a[2];
#pragma unroll
            for (int rt = 0; rt < 2; ++rt)
                a[rt] = *(const bf16x8*)&A0[(long long)arow[rt] * K + kk + quad * 8];
#pragma unroll
            for (int ct = 0; ct < 4; ++ct) {
                bf16x8 b = *(const bf16x8*)&Bs[(ct * 16 + ln) * KP + kk + quad * 8];
#pragma unroll
                for (int rt = 0; rt < 2; ++rt)
                    acc[rt][ct] = __builtin_amdgcn_mfma_f32_16x16x32_bf16(a[rt], b, acc[rt][ct], 0, 0, 0);
            }
        }

        // per-phase epilogue (no bias here)
#pragma unroll
        for (int rt = 0; rt < 2; ++rt) {
            int rbase = bm0 + wave * 32 + rt * 16 + quad * 4;
#pragma unroll
            for (int ct = 0; ct < 3; ++ct) {  // cols >= 48 are all padding
                int col = ct * 16 + ln;
                if (col >= O) continue;
#pragma unroll
                for (int r = 0; r < 4; ++r) {
                    int row = rbase + r;
                    if (row >= N) continue;
                    if (phase == 0)
                        P[(long long)row * O + col] = f2bf(acc[rt][ct][r]);
                    else
                        S[(long long)row * O + col] = acc[rt][ct][r];
                }
            }
        }
    }
}

// ---------------- fused mean-agg(D=40) + self + bias + log_softmax ----------------
__global__ __launch_bounds__(256) void agg_bias_lsm(const ushort* __restrict__ P,
                                                    const float* __restrict__ S,
                                                    const float* __restrict__ bias,
                                                    const int* __restrict__ rowptr,
                                                    const int* __restrict__ srcs,
                                                    const float* __restrict__ inv,
                                                    float* __restrict__ out, int N) {
    const int wave = threadIdx.x >> 6;
    const int lane = threadIdx.x & 63;
    const int n = blockIdx.x * 4 + wave;
    if (n >= N) return;
    const int beg = rowptr[n];
    const int end = rowptr[n + 1];
    const bool act = lane < OUT_DIM;
    const int cidx = act ? lane : 0;

    float acc = 0.f;
    int e = beg;
    for (; e + 3 < end; e += 4) {
        int s0 = srcs[e], s1 = srcs[e + 1], s2 = srcs[e + 2], s3 = srcs[e + 3];
        float v0 = bfl((uint)P[(long long)s0 * OUT_DIM + cidx] << 16 >> 16 << 16);
        // (simple form below; compiler folds)
        v0 = __builtin_bit_cast(float, (uint)P[(long long)s0 * OUT_DIM + cidx] << 16);
        float v1 = __builtin_bit_cast(float, (uint)P[(long long)s1 * OUT_DIM + cidx] << 16);
        float v2 = __builtin_bit_cast(float, (uint)P[(long long)s2 * OUT_DIM + cidx] << 16);
        float v3 = __builtin_bit_cast(float, (uint)P[(long long)s3 * OUT_DIM + cidx] << 16);
        acc += (v0 + v1) + (v2 + v3);
    }
    for (; e < end; ++e)
        acc += __builtin_bit_cast(float, (uint)P[(long long)srcs[e] * OUT_DIM + cidx] << 16);

    float v = act ? (acc * inv[n] + S[(long long)n * OUT_DIM + lane] + bias[lane]) : -INFINITY;
    float m = v;
#pragma unroll
    for (int o = 32; o > 0; o >>= 1) m = fmaxf(m, __shfl_xor(m, o, 64));
    float ex = act ? expf(v - m) : 0.f;
    float sm = ex;
#pragma unroll
    for (int o = 32; o > 0; o >>= 1) sm += __shfl_xor(sm, o, 64);
    float ls = logf(sm);
    if (act) out[(long long)n * OUT_DIM + lane] = v - m - ls;
}

extern "C" void kernel_launch(void* const* d_in, const int* in_sizes, int n_in,
                              void* d_out, int out_size, void* d_ws, size_t ws_size,
                              hipStream_t stream) {
    const float* x   = (const float*)d_in[0];
    const int*   ei  = (const int*)d_in[1];
    const float* Wl1 = (const float*)d_in[2];
    const float* bl1 = (const float*)d_in[3];
    const float* Wr1 = (const float*)d_in[4];
    const float* Wl2 = (const float*)d_in[5];
    const float* bl2 = (const float*)d_in[6];
    const float* Wr2 = (const float*)d_in[7];
    const float* Wl3 = (const float*)d_in[8];
    const float* bl3 = (const float*)d_in[9];
    const float* Wr3 = (const float*)d_in[10];
    float* out = (float*)d_out;

    const int N = in_sizes[0] / IN_DIM;  // 50000
    const int E = in_sizes[1] / 2;       // 600000
    const int* src = ei;
    const int* dst = ei + E;

    // ---- workspace layout ----
    char* w = (char*)d_ws;
    size_t off = 0;
    auto alloc = [&](size_t bytes) {
        void* p = w + off;
        off = (off + bytes + 255) & ~(size_t)255;
        return p;
    };
    ushort* xb   = (ushort*)alloc((size_t)N * IN_DIM * 2);
    ushort* M    = (ushort*)alloc((size_t)N * HID_DIM * 2);
    ushort* H1   = (ushort*)alloc((size_t)N * HID_DIM * 2);
    ushort* H2   = (ushort*)alloc((size_t)N * HID_DIM * 2);
    ushort* P3   = (ushort*)alloc((size_t)N * OUT_DIM * 2);
    float*  S3   = (float*)alloc((size_t)N * OUT_DIM * 4);
    float*  inv  = (float*)alloc((size_t)N * 4);
    int*    cnt  = (int*)alloc((size_t)N * 4);
    int*    rowptr = (int*)alloc((size_t)(N + 1) * 4);
    int*    cursor = (int*)alloc((size_t)N * 4);
    int*    srcs = (int*)alloc((size_t)E * 4);
    int*    bsum = (int*)alloc(256 * 4);
    ushort* Wl1b = (ushort*)alloc(256 * 128 * 2);
    ushort* Wr1b = (ushort*)alloc(256 * 128 * 2);
    ushort* Wl2b = (ushort*)alloc(256 * 256 * 2);
    ushort* Wr2b = (ushort*)alloc(256 * 256 * 2);
    ushort* Wl3b = (ushort*)alloc(64 * 256 * 2);
    ushort* Wr3b = (ushort*)alloc(64 * 256 * 2);

    // ---- conversions ----
    cvt_x<<<(N * IN_DIM / 4 + 255) / 256, 256, 0, stream>>>(x, xb, N * IN_DIM / 4);
    cvt_w2<<<(256 * 128 + 255) / 256, 256, 0, stream>>>(Wl1, Wr1, Wl1b, Wr1b, 256, 256, 128);
    cvt_w2<<<(256 * 256 + 255) / 256, 256, 0, stream>>>(Wl2, Wr2, Wl2b, Wr2b, 256, 256, 256);
    cvt_w2<<<(64 * 256 + 255) / 256, 256, 0, stream>>>(Wl3, Wr3, Wl3b, Wr3b, 40, 64, 256);

    // ---- CSR build (parallel 3-pass scan) ----
    const int SB = (N + SCAN_CHUNK - 1) / SCAN_CHUNK;  // 25
    hipMemsetAsync(cnt, 0, (size_t)N * sizeof(int), stream);
    hist_kernel<<<(E + 255) / 256, 256, 0, stream>>>(dst, cnt, E);
    scan_pass1<<<SB, 256, 0, stream>>>(cnt, bsum, N);
    scan_pass2<<<1, 256, 0, stream>>>(bsum, SB);
    scan_pass3<<<SB, 256, 0, stream>>>(cnt, bsum, rowptr, cursor, inv, N, E);
    fill_kernel<<<(E + 255) / 256, 256, 0, stream>>>(src, dst, cursor, srcs, E);

    const int gm = (N + 127) / 128;  // 391
    const int gg = (N + 3) / 4;

    // ---- layer 1: K=128 -> 256, relu ----
    gather_mean_bf<IN_DIM><<<gg, 256, 0, stream>>>(xb, rowptr, srcs, inv, M, N);
    sage_gemm_mfma<IN_DIM, true, true><<<dim3(gm, 4), 256, 0, stream>>>(
        M, xb, Wl1b, bl1, Wr1b, H1, N, HID_DIM);

    // ---- layer 2: K=256 -> 256, relu ----
    gather_mean_bf<HID_DIM><<<gg, 256, 0, stream>>>(H1, rowptr, srcs, inv, M, N);
    sage_gemm_mfma<HID_DIM, true, true><<<dim3(gm, 4), 256, 0, stream>>>(
        M, H1, Wl2b, bl2, Wr2b, H2, N, HID_DIM);

    // ---- layer 3 (GEMM-first): P3 = H2@Wl3^T, S3 = H2@Wr3^T, then fused agg+lsm ----
    sage_gemm_pre<HID_DIM><<<dim3(gm, 1), 256, 0, stream>>>(
        H2, Wl3b, Wr3b, P3, S3, N, OUT_DIM);
    agg_bias_lsm<<<gg, 256, 0, stream>>>(P3, S3, bl3, rowptr, srcs, inv, out, N);
}

// Round 7
// 371.999 us; speedup vs baseline: 14.8816x; 1.0198x over previous
//
#include <hip/hip_runtime.h>
#include <hip/hip_bf16.h>

#define IN_DIM 128
#define HID_DIM 256
#define OUT_DIM 40
#define SCAN_CHUNK 2048

typedef __attribute__((ext_vector_type(8))) __bf16 bf16x8;
typedef __attribute__((ext_vector_type(4))) float f32x4;

__device__ inline ushort f2bf(float f) {
    uint u = __builtin_bit_cast(uint, f);
    u = (u + 0x7fff + ((u >> 16) & 1)) >> 16;
    return (ushort)u;
}
__device__ inline float bfl(uint u) { return __builtin_bit_cast(float, u << 16); }
__device__ inline float bfh(uint u) { return __builtin_bit_cast(float, u & 0xffff0000u); }

// ---------------- input/weight conversion ----------------
__global__ __launch_bounds__(256) void cvt_x(const float* __restrict__ in,
                                             ushort* __restrict__ out, int n4) {
    int i = blockIdx.x * 256 + threadIdx.x;
    if (i < n4) {
        float4 v = ((const float4*)in)[i];
        uint2 o;
        o.x = (uint)f2bf(v.x) | ((uint)f2bf(v.y) << 16);
        o.y = (uint)f2bf(v.z) | ((uint)f2bf(v.w) << 16);
        ((uint2*)out)[i] = o;
    }
}

__global__ __launch_bounds__(256) void cvt_w2(const float* __restrict__ wl,
                                              const float* __restrict__ wr,
                                              ushort* __restrict__ ol,
                                              ushort* __restrict__ orr,
                                              int O, int OPAD, int K) {
    int idx = blockIdx.x * 256 + threadIdx.x;
    int tot = OPAD * K;
    if (idx >= tot) return;
    int row = idx / K;
    int col = idx - row * K;
    ushort vl = 0, vr = 0;
    if (row < O) {
        vl = f2bf(wl[row * K + col]);
        vr = f2bf(wr[row * K + col]);
    }
    ol[idx] = vl;
    orr[idx] = vr;
}

// ---------------- CSR build ----------------
__global__ __launch_bounds__(256) void hist_kernel(const int* __restrict__ dst,
                                                   int* __restrict__ cnt, int E) {
    int e = blockIdx.x * 256 + threadIdx.x;
    if (e < E) atomicAdd(&cnt[dst[e]], 1);
}

__global__ __launch_bounds__(256) void scan_pass1(const int* __restrict__ cnt,
                                                  int* __restrict__ bsum, int N) {
    __shared__ int red[256];
    const int base = blockIdx.x * SCAN_CHUNK;
    int s = 0;
    for (int i = threadIdx.x; i < SCAN_CHUNK; i += 256) {
        int idx = base + i;
        if (idx < N) s += cnt[idx];
    }
    red[threadIdx.x] = s;
    __syncthreads();
    for (int o = 128; o > 0; o >>= 1) {
        if (threadIdx.x < o) red[threadIdx.x] += red[threadIdx.x + o];
        __syncthreads();
    }
    if (threadIdx.x == 0) bsum[blockIdx.x] = red[0];
}

__global__ __launch_bounds__(256) void scan_pass2(int* __restrict__ bsum, int B) {
    __shared__ int ls[256];
    const int t = threadIdx.x;
    int v = (t < B) ? bsum[t] : 0;
    ls[t] = v;
    __syncthreads();
    for (int o = 1; o < 256; o <<= 1) {
        int u = (t >= o) ? ls[t - o] : 0;
        __syncthreads();
        ls[t] += u;
        __syncthreads();
    }
    if (t < B) bsum[t] = ls[t] - v;  // exclusive
}

__global__ __launch_bounds__(256) void scan_pass3(const int* __restrict__ cnt,
                                                  const int* __restrict__ bsum,
                                                  int* __restrict__ rowptr,
                                                  int* __restrict__ cursor,
                                                  float* __restrict__ inv, int N, int E) {
    __shared__ int ls[256];
    const int tbase = blockIdx.x * SCAN_CHUNK + threadIdx.x * 8;
    int c[8];
    int s = 0;
#pragma unroll
    for (int j = 0; j < 8; ++j) {
        int idx = tbase + j;
        c[j] = (idx < N) ? cnt[idx] : 0;
        s += c[j];
    }
    ls[threadIdx.x] = s;
    __syncthreads();
    for (int o = 1; o < 256; o <<= 1) {
        int u = (threadIdx.x >= o) ? ls[threadIdx.x - o] : 0;
        __syncthreads();
        ls[threadIdx.x] += u;
        __syncthreads();
    }
    int run = bsum[blockIdx.x] + ls[threadIdx.x] - s;
#pragma unroll
    for (int j = 0; j < 8; ++j) {
        int idx = tbase + j;
        if (idx < N) {
            rowptr[idx] = run;
            cursor[idx] = run;
            inv[idx] = 1.0f / fmaxf((float)c[j], 1.0f);
            run += c[j];
        }
    }
    if (blockIdx.x == 0 && threadIdx.x == 0) rowptr[N] = E;
}

__global__ __launch_bounds__(256) void fill_kernel(const int* __restrict__ src,
                                                   const int* __restrict__ dst,
                                                   int* __restrict__ cursor,
                                                   int* __restrict__ srcs, int E) {
    int e = blockIdx.x * 256 + threadIdx.x;
    if (e < E) {
        int pos = atomicAdd(&cursor[dst[e]], 1);
        srcs[pos] = src[e];
    }
}

// ---------------- gather mean (bf16 in/out, fp32 accumulate, 4-wide ILP) ----------------
template <int D>
__global__ __launch_bounds__(256) void gather_mean_bf(const ushort* __restrict__ feat,
                                                      const int* __restrict__ rowptr,
                                                      const int* __restrict__ srcs,
                                                      const float* __restrict__ inv,
                                                      ushort* __restrict__ out, int N) {
    constexpr int V = D / 64;  // bf16 per lane: 2 or 4
    const int wave = threadIdx.x >> 6;
    const int lane = threadIdx.x & 63;
    const int n = blockIdx.x * 4 + wave;
    if (n >= N) return;
    const int beg = rowptr[n];
    const int end = rowptr[n + 1];
    const int col = lane * V;
    float a0 = 0.f, a1 = 0.f, a2 = 0.f, a3 = 0.f;
    int e = beg;
    if constexpr (V == 4) {
        for (; e + 3 < end; e += 4) {
            int s0 = srcs[e], s1 = srcs[e + 1], s2 = srcs[e + 2], s3 = srcs[e + 3];
            uint2 q0 = *(const uint2*)&feat[(long long)s0 * D + col];
            uint2 q1 = *(const uint2*)&feat[(long long)s1 * D + col];
            uint2 q2 = *(const uint2*)&feat[(long long)s2 * D + col];
            uint2 q3 = *(const uint2*)&feat[(long long)s3 * D + col];
            a0 += (bfl(q0.x) + bfl(q1.x)) + (bfl(q2.x) + bfl(q3.x));
            a1 += (bfh(q0.x) + bfh(q1.x)) + (bfh(q2.x) + bfh(q3.x));
            a2 += (bfl(q0.y) + bfl(q1.y)) + (bfl(q2.y) + bfl(q3.y));
            a3 += (bfh(q0.y) + bfh(q1.y)) + (bfh(q2.y) + bfh(q3.y));
        }
        for (; e + 1 < end; e += 2) {
            int s0 = srcs[e], s1 = srcs[e + 1];
            uint2 q0 = *(const uint2*)&feat[(long long)s0 * D + col];
            uint2 q1 = *(const uint2*)&feat[(long long)s1 * D + col];
            a0 += bfl(q0.x) + bfl(q1.x);
            a1 += bfh(q0.x) + bfh(q1.x);
            a2 += bfl(q0.y) + bfl(q1.y);
            a3 += bfh(q0.y) + bfh(q1.y);
        }
        if (e < end) {
            uint2 q0 = *(const uint2*)&feat[(long long)srcs[e] * D + col];
            a0 += bfl(q0.x); a1 += bfh(q0.x); a2 += bfl(q0.y); a3 += bfh(q0.y);
        }
        const float sc = inv[n];
        uint2 o;
        o.x = (uint)f2bf(a0 * sc) | ((uint)f2bf(a1 * sc) << 16);
        o.y = (uint)f2bf(a2 * sc) | ((uint)f2bf(a3 * sc) << 16);
        *(uint2*)&out[(long long)n * D + col] = o;
    } else {
        for (; e + 3 < end; e += 4) {
            int s0 = srcs[e], s1 = srcs[e + 1], s2 = srcs[e + 2], s3 = srcs[e + 3];
            uint q0 = *(const uint*)&feat[(long long)s0 * D + col];
            uint q1 = *(const uint*)&feat[(long long)s1 * D + col];
            uint q2 = *(const uint*)&feat[(long long)s2 * D + col];
            uint q3 = *(const uint*)&feat[(long long)s3 * D + col];
            a0 += (bfl(q0) + bfl(q1)) + (bfl(q2) + bfl(q3));
            a1 += (bfh(q0) + bfh(q1)) + (bfh(q2) + bfh(q3));
        }
        for (; e + 1 < end; e += 2) {
            int s0 = srcs[e], s1 = srcs[e + 1];
            uint q0 = *(const uint*)&feat[(long long)s0 * D + col];
            uint q1 = *(const uint*)&feat[(long long)s1 * D + col];
            a0 += bfl(q0) + bfl(q1);
            a1 += bfh(q0) + bfh(q1);
        }
        if (e < end) {
            uint q0 = *(const uint*)&feat[(long long)srcs[e] * D + col];
            a0 += bfl(q0); a1 += bfh(q0);
        }
        const float sc = inv[n];
        uint o = (uint)f2bf(a0 * sc) | ((uint)f2bf(a1 * sc) << 16);
        *(uint*)&out[(long long)n * D + col] = o;
    }
}

// ---------------- MFMA SAGE GEMM (A register-prefetched, W in LDS) ----------------
// out[m][o] = act( sum_k Amean[m][k]*Wl[o][k] + bias[o] + sum_k Aself[m][k]*Wr[o][k] )
// Per phase: the wave's whole A-strip is prefetched into registers (K/32 x 2
// fragments = 16 independent global loads in flight), THEN W is staged into
// LDS; the K-loop is pure ds_read_b128 + MFMA with no global access.
template <int K, bool RELU, bool OUTBF>
__global__ __launch_bounds__(256, 3) void sage_gemm_mfma(const ushort* __restrict__ Amean,
                                                         const ushort* __restrict__ Aself,
                                                         const ushort* __restrict__ Wl,
                                                         const float* __restrict__ bias,
                                                         const ushort* __restrict__ Wr,
                                                         void* __restrict__ outv, int N, int O) {
    constexpr int KP = K + 8;   // padded LDS row
    constexpr int NK = K / 32;  // k-steps
    __shared__ __align__(16) ushort Bs[64 * KP];

    const int tid = threadIdx.x;
    const int wave = tid >> 6;
    const int lane = tid & 63;
    const int ln = lane & 15;
    const int quad = lane >> 4;
    const int bm0 = blockIdx.x * 128;
    const int bn0 = blockIdx.y * 64;

    int arow[2];
#pragma unroll
    for (int rt = 0; rt < 2; ++rt) {
        int r = bm0 + wave * 32 + rt * 16 + ln;
        arow[rt] = min(r, N - 1);
    }

    f32x4 acc[2][4] = {};

    for (int phase = 0; phase < 2; ++phase) {
        const ushort* __restrict__ A = phase ? Aself : Amean;
        const ushort* __restrict__ W = phase ? Wr : Wl;

        // prefetch the whole A strip for this phase (independent loads)
        bf16x8 areg[NK][2];
#pragma unroll
        for (int kk = 0; kk < NK; ++kk)
#pragma unroll
            for (int rt = 0; rt < 2; ++rt)
                areg[kk][rt] = *(const bf16x8*)&A[(long long)arow[rt] * K + kk * 32 + quad * 8];

        __syncthreads();  // Bs free (previous phase's readers done)
#pragma unroll
        for (int i = tid; i < 64 * (K / 8); i += 256) {
            int row = i / (K / 8);
            int c8 = (i % (K / 8)) * 8;
            *(ulonglong2*)&Bs[row * KP + c8] =
                *(const ulonglong2*)&W[(long long)(bn0 + row) * K + c8];
        }
        __syncthreads();

#pragma unroll
        for (int kk = 0; kk < NK; ++kk) {
#pragma unroll
            for (int ct = 0; ct < 4; ++ct) {
                bf16x8 b = *(const bf16x8*)&Bs[(ct * 16 + ln) * KP + kk * 32 + quad * 8];
#pragma unroll
                for (int rt = 0; rt < 2; ++rt)
                    acc[rt][ct] = __builtin_amdgcn_mfma_f32_16x16x32_bf16(areg[kk][rt], b, acc[rt][ct], 0, 0, 0);
            }
        }
    }

#pragma unroll
    for (int rt = 0; rt < 2; ++rt) {
        int rbase = bm0 + wave * 32 + rt * 16 + quad * 4;
#pragma unroll
        for (int ct = 0; ct < 4; ++ct) {
            int col = bn0 + ct * 16 + ln;
            if (col >= O) continue;
            float bv = bias[col];
#pragma unroll
            for (int r = 0; r < 4; ++r) {
                int row = rbase + r;
                if (row >= N) continue;
                float v = acc[rt][ct][r] + bv;
                if (RELU) v = fmaxf(v, 0.f);
                if (OUTBF)
                    ((ushort*)outv)[(long long)row * O + col] = f2bf(v);
                else
                    ((float*)outv)[(long long)row * O + col] = v;
            }
        }
    }
}

// ---------------- layer-3 pre-aggregation GEMM: P = A@Wl^T (bf16), S = A@Wr^T (fp32) ----------------
template <int K>
__global__ __launch_bounds__(256, 3) void sage_gemm_pre(const ushort* __restrict__ A0,
                                                        const ushort* __restrict__ Wl,
                                                        const ushort* __restrict__ Wr,
                                                        ushort* __restrict__ P,
                                                        float* __restrict__ S, int N, int O) {
    constexpr int KP = K + 8;
    constexpr int NK = K / 32;
    __shared__ __align__(16) ushort Bs[64 * KP];

    const int tid = threadIdx.x;
    const int wave = tid >> 6;
    const int lane = tid & 63;
    const int ln = lane & 15;
    const int quad = lane >> 4;
    const int bm0 = blockIdx.x * 128;

    int arow[2];
#pragma unroll
    for (int rt = 0; rt < 2; ++rt) {
        int r = bm0 + wave * 32 + rt * 16 + ln;
        arow[rt] = min(r, N - 1);
    }

    // A strip is the same for both phases here: prefetch once
    bf16x8 areg[NK][2];
#pragma unroll
    for (int kk = 0; kk < NK; ++kk)
#pragma unroll
        for (int rt = 0; rt < 2; ++rt)
            areg[kk][rt] = *(const bf16x8*)&A0[(long long)arow[rt] * K + kk * 32 + quad * 8];

    for (int phase = 0; phase < 2; ++phase) {
        const ushort* __restrict__ W = phase ? Wr : Wl;

        __syncthreads();
#pragma unroll
        for (int i = tid; i < 64 * (K / 8); i += 256) {
            int row = i / (K / 8);
            int c8 = (i % (K / 8)) * 8;
            *(ulonglong2*)&Bs[row * KP + c8] =
                *(const ulonglong2*)&W[(long long)row * K + c8];
        }
        __syncthreads();

        f32x4 acc[2][4] = {};
#pragma unroll
        for (int kk = 0; kk < NK; ++kk) {
#pragma unroll
            for (int ct = 0; ct < 4; ++ct) {
                bf16x8 b = *(const bf16x8*)&Bs[(ct * 16 + ln) * KP + kk * 32 + quad * 8];
#pragma unroll
                for (int rt = 0; rt < 2; ++rt)
                    acc[rt][ct] = __builtin_amdgcn_mfma_f32_16x16x32_bf16(areg[kk][rt], b, acc[rt][ct], 0, 0, 0);
            }
        }

#pragma unroll
        for (int rt = 0; rt < 2; ++rt) {
            int rbase = bm0 + wave * 32 + rt * 16 + quad * 4;
#pragma unroll
            for (int ct = 0; ct < 3; ++ct) {  // cols >= 48 are padding
                int col = ct * 16 + ln;
                if (col >= O) continue;
#pragma unroll
                for (int r = 0; r < 4; ++r) {
                    int row = rbase + r;
                    if (row >= N) continue;
                    if (phase == 0)
                        P[(long long)row * O + col] = f2bf(acc[rt][ct][r]);
                    else
                        S[(long long)row * O + col] = acc[rt][ct][r];
                }
            }
        }
    }
}

// ---------------- fused mean-agg(D=40) + self + bias + log_softmax ----------------
__global__ __launch_bounds__(256) void agg_bias_lsm(const ushort* __restrict__ P,
                                                    const float* __restrict__ S,
                                                    const float* __restrict__ bias,
                                                    const int* __restrict__ rowptr,
                                                    const int* __restrict__ srcs,
                                                    const float* __restrict__ inv,
                                                    float* __restrict__ out, int N) {
    const int wave = threadIdx.x >> 6;
    const int lane = threadIdx.x & 63;
    const int n = blockIdx.x * 4 + wave;
    if (n >= N) return;
    const int beg = rowptr[n];
    const int end = rowptr[n + 1];
    const bool act = lane < OUT_DIM;
    const int cidx = act ? lane : 0;

    float acc = 0.f;
    int e = beg;
    for (; e + 3 < end; e += 4) {
        int s0 = srcs[e], s1 = srcs[e + 1], s2 = srcs[e + 2], s3 = srcs[e + 3];
        float v0 = __builtin_bit_cast(float, (uint)P[(long long)s0 * OUT_DIM + cidx] << 16);
        float v1 = __builtin_bit_cast(float, (uint)P[(long long)s1 * OUT_DIM + cidx] << 16);
        float v2 = __builtin_bit_cast(float, (uint)P[(long long)s2 * OUT_DIM + cidx] << 16);
        float v3 = __builtin_bit_cast(float, (uint)P[(long long)s3 * OUT_DIM + cidx] << 16);
        acc += (v0 + v1) + (v2 + v3);
    }
    for (; e < end; ++e)
        acc += __builtin_bit_cast(float, (uint)P[(long long)srcs[e] * OUT_DIM + cidx] << 16);

    float v = act ? (acc * inv[n] + S[(long long)n * OUT_DIM + lane] + bias[lane]) : -INFINITY;
    float m = v;
#pragma unroll
    for (int o = 32; o > 0; o >>= 1) m = fmaxf(m, __shfl_xor(m, o, 64));
    float ex = act ? expf(v - m) : 0.f;
    float sm = ex;
#pragma unroll
    for (int o = 32; o > 0; o >>= 1) sm += __shfl_xor(sm, o, 64);
    float ls = logf(sm);
    if (act) out[(long long)n * OUT_DIM + lane] = v - m - ls;
}

extern "C" void kernel_launch(void* const* d_in, const int* in_sizes, int n_in,
                              void* d_out, int out_size, void* d_ws, size_t ws_size,
                              hipStream_t stream) {
    const float* x   = (const float*)d_in[0];
    const int*   ei  = (const int*)d_in[1];
    const float* Wl1 = (const float*)d_in[2];
    const float* bl1 = (const float*)d_in[3];
    const float* Wr1 = (const float*)d_in[4];
    const float* Wl2 = (const float*)d_in[5];
    const float* bl2 = (const float*)d_in[6];
    const float* Wr2 = (const float*)d_in[7];
    const float* Wl3 = (const float*)d_in[8];
    const float* bl3 = (const float*)d_in[9];
    const float* Wr3 = (const float*)d_in[10];
    float* out = (float*)d_out;

    const int N = in_sizes[0] / IN_DIM;  // 50000
    const int E = in_sizes[1] / 2;       // 600000
    const int* src = ei;
    const int* dst = ei + E;

    // ---- workspace layout ----
    char* w = (char*)d_ws;
    size_t off = 0;
    auto alloc = [&](size_t bytes) {
        void* p = w + off;
        off = (off + bytes + 255) & ~(size_t)255;
        return p;
    };
    ushort* xb   = (ushort*)alloc((size_t)N * IN_DIM * 2);
    ushort* M    = (ushort*)alloc((size_t)N * HID_DIM * 2);
    ushort* H1   = (ushort*)alloc((size_t)N * HID_DIM * 2);
    ushort* H2   = (ushort*)alloc((size_t)N * HID_DIM * 2);
    ushort* P3   = (ushort*)alloc((size_t)N * OUT_DIM * 2);
    float*  S3   = (float*)alloc((size_t)N * OUT_DIM * 4);
    float*  inv  = (float*)alloc((size_t)N * 4);
    int*    cnt  = (int*)alloc((size_t)N * 4);
    int*    rowptr = (int*)alloc((size_t)(N + 1) * 4);
    int*    cursor = (int*)alloc((size_t)N * 4);
    int*    srcs = (int*)alloc((size_t)E * 4);
    int*    bsum = (int*)alloc(256 * 4);
    ushort* Wl1b = (ushort*)alloc(256 * 128 * 2);
    ushort* Wr1b = (ushort*)alloc(256 * 128 * 2);
    ushort* Wl2b = (ushort*)alloc(256 * 256 * 2);
    ushort* Wr2b = (ushort*)alloc(256 * 256 * 2);
    ushort* Wl3b = (ushort*)alloc(64 * 256 * 2);
    ushort* Wr3b = (ushort*)alloc(64 * 256 * 2);

    // ---- conversions ----
    cvt_x<<<(N * IN_DIM / 4 + 255) / 256, 256, 0, stream>>>(x, xb, N * IN_DIM / 4);
    cvt_w2<<<(256 * 128 + 255) / 256, 256, 0, stream>>>(Wl1, Wr1, Wl1b, Wr1b, 256, 256, 128);
    cvt_w2<<<(256 * 256 + 255) / 256, 256, 0, stream>>>(Wl2, Wr2, Wl2b, Wr2b, 256, 256, 256);
    cvt_w2<<<(64 * 256 + 255) / 256, 256, 0, stream>>>(Wl3, Wr3, Wl3b, Wr3b, 40, 64, 256);

    // ---- CSR build (parallel 3-pass scan) ----
    const int SB = (N + SCAN_CHUNK - 1) / SCAN_CHUNK;  // 25
    hipMemsetAsync(cnt, 0, (size_t)N * sizeof(int), stream);
    hist_kernel<<<(E + 255) / 256, 256, 0, stream>>>(dst, cnt, E);
    scan_pass1<<<SB, 256, 0, stream>>>(cnt, bsum, N);
    scan_pass2<<<1, 256, 0, stream>>>(bsum, SB);
    scan_pass3<<<SB, 256, 0, stream>>>(cnt, bsum, rowptr, cursor, inv, N, E);
    fill_kernel<<<(E + 255) / 256, 256, 0, stream>>>(src, dst, cursor, srcs, E);

    const int gm = (N + 127) / 128;  // 391
    const int gg = (N + 3) / 4;

    // ---- layer 1: K=128 -> 256, relu ----
    gather_mean_bf<IN_DIM><<<gg, 256, 0, stream>>>(xb, rowptr, srcs, inv, M, N);
    sage_gemm_mfma<IN_DIM, true, true><<<dim3(gm, 4), 256, 0, stream>>>(
        M, xb, Wl1b, bl1, Wr1b, H1, N, HID_DIM);

    // ---- layer 2: K=256 -> 256, relu ----
    gather_mean_bf<HID_DIM><<<gg, 256, 0, stream>>>(H1, rowptr, srcs, inv, M, N);
    sage_gemm_mfma<HID_DIM, true, true><<<dim3(gm, 4), 256, 0, stream>>>(
        M, H1, Wl2b, bl2, Wr2b, H2, N, HID_DIM);

    // ---- layer 3 (GEMM-first): P3 = H2@Wl3^T, S3 = H2@Wr3^T, then fused agg+lsm ----
    sage_gemm_pre<HID_DIM><<<dim3(gm, 1), 256, 0, stream>>>(
        H2, Wl3b, Wr3b, P3, S3, N, OUT_DIM);
    agg_bias_lsm<<<gg, 256, 0, stream>>>(P3, S3, bl3, rowptr, srcs, inv, out, N);
}